// Round 12
// baseline (1341.176 us; speedup 1.0000x reference)
//
#include <hip/hip_runtime.h>
#include <math.h>

// Problem constants
#define BSZ 8
#define LSZ 2048
#define DMV 320
#define DIV 1280
#define NST 16
#define DCV 8
#define DTR 20
#define NBLKV 4
#define MTOT (BSZ*LSZ)   // 16384
#define NCHUNK 64
#define CLEN 32          // NCHUNK*CLEN == LSZ
#define DBLD 56          // dbc leading dim (bf16), 16B-aligned rows

typedef __attribute__((ext_vector_type(8))) short short8;
typedef __attribute__((ext_vector_type(8))) unsigned short ushort8;
typedef __attribute__((ext_vector_type(4))) float floatx4;

__device__ inline unsigned short f2bf(float f) {
    union { float f; unsigned u; } v; v.f = f;
    unsigned r = v.u + 0x7FFFu + ((v.u >> 16) & 1u);
    return (unsigned short)(r >> 16);
}
__device__ inline float bf2f(unsigned short b) {
    union { unsigned u; float f; } v; v.u = ((unsigned)b) << 16;
    return v.f;
}

// async 16B global -> LDS (wave-uniform LDS base + lane*16) [m97 pattern]
__device__ __forceinline__ void gload_lds16(unsigned short* l, const unsigned short* g) {
    __builtin_amdgcn_global_load_lds(
        (const __attribute__((address_space(1))) unsigned int*)g,
        (__attribute__((address_space(3))) unsigned int*)l, 16, 0, 0);
}

// ---------------------------------------------------------------------------
// fp32 -> bf16 weight conversion (grid-stride, n % 4 == 0)
// ---------------------------------------------------------------------------
__global__ __launch_bounds__(256) void convert_kernel(
    const float* __restrict__ src, unsigned short* __restrict__ dst, long n4) {
    long i = (long)blockIdx.x * 256 + threadIdx.x;
    if (i >= n4) return;
    float4 v = *(const float4*)(src + i * 4);
    unsigned short o[4] = {f2bf(v.x), f2bf(v.y), f2bf(v.z), f2bf(v.w)};
    *(unsigned long long*)(dst + i * 4) = *(unsigned long long*)o;
}

// dtproj_w (NBLKV x 1280 x 20) -> bf16 padded (NBLKV x 1280 x 32), zero cols 20..31
__global__ __launch_bounds__(256) void convert_dtw_kernel(
    const float* __restrict__ src, unsigned short* __restrict__ dst) {
    int i = blockIdx.x * 256 + threadIdx.x;
    if (i >= NBLKV * DIV * 32) return;
    int l = i / (DIV * 32), rem = i % (DIV * 32);
    int d = rem >> 5, j = rem & 31;
    dst[i] = (j < DTR) ? f2bf(src[((long)l * DIV + d) * DTR + j]) : (unsigned short)0;
}

// xproj_w (NBLKV x 52 x 1280) -> bf16 padded (NBLKV x 64 x 1280), zero rows 52..63
__global__ __launch_bounds__(256) void convert_xp_kernel(
    const float* __restrict__ src, unsigned short* __restrict__ dst) {
    int i = blockIdx.x * 256 + threadIdx.x;
    if (i >= NBLKV * 64 * DIV) return;
    int l = i / (64 * DIV), rem = i % (64 * DIV);
    int n = rem / DIV, k = rem % DIV;
    dst[i] = (n < DTR + 2 * NST) ? f2bf(src[((long)l * (DTR + 2 * NST) + n) * DIV + k])
                                 : (unsigned short)0;
}

// head weight (N x K) fp32 -> pair-packed transposed bf16
__global__ __launch_bounds__(256) void convert_t2_kernel(
    const float* __restrict__ src, unsigned short* __restrict__ dst, int N, int K) {
    int i = blockIdx.x * 256 + threadIdx.x;
    if (i >= N * K) return;
    int n = i / K, k = i % K;
    dst[((k >> 1) * N + n) * 2 + (k & 1)] = f2bf(src[i]);
}

// ---------------------------------------------------------------------------
// start_max reduction (x[:,:,2] >= 0, so int-compare atomicMax is valid)
// ---------------------------------------------------------------------------
__global__ void init_sm_kernel(float* sm) {
    if (threadIdx.x == 0) ((int*)sm)[0] = 0;
}

__global__ void reduce_max_kernel(const float* __restrict__ x, float* sm) {
    int idx = blockIdx.x * blockDim.x + threadIdx.x;
    float v = 0.f;
    for (int i = idx; i < MTOT; i += gridDim.x * blockDim.x)
        v = fmaxf(v, x[i * 4 + 2]);
    #pragma unroll
    for (int off = 32; off > 0; off >>= 1)
        v = fmaxf(v, __shfl_xor(v, off, 64));
    if ((threadIdx.x & 63) == 0)
        atomicMax((int*)sm, __float_as_int(v));
}

// ---------------------------------------------------------------------------
// input normalize + fc (K=4) -> bf16 u
// ---------------------------------------------------------------------------
__global__ __launch_bounds__(256) void fc_kernel(
    const float* __restrict__ x, const float* __restrict__ fw,
    const float* __restrict__ fb, const float* __restrict__ sm,
    unsigned short* __restrict__ u) {
    int o = blockIdx.x * 64 + (threadIdx.x & 63);
    long m = (long)blockIdx.y * 4 + (threadIdx.x >> 6);
    float inv_sm = 1.0f / sm[0];
    float x0 = x[m * 4 + 0] * (1.0f / 255.0f);
    float x1 = x[m * 4 + 1] * (1.0f / 255.0f);
    float x2 = x[m * 4 + 2] * inv_sm;
    float x3 = x[m * 4 + 3];
    float acc = fb[o];
    acc = fmaf(x0, fw[o * 4 + 0], acc);
    acc = fmaf(x1, fw[o * 4 + 1], acc);
    acc = fmaf(x2, fw[o * 4 + 2], acc);
    acc = fmaf(x3, fw[o * 4 + 3], acc);
    u[m * DMV + o] = f2bf(acc);
}

// ---------------------------------------------------------------------------
// bf16 MFMA GEMM with async global->LDS staging + XOR chunk swizzle.
// Epilogue: LDS transpose (32-row groups, reusing Xs) -> coalesced ushort8
// stores (16B/lane). Row-capacity guard n0+cb+8 <= ldy handles xproj ld=56.
// ---------------------------------------------------------------------------
template<int ACT, int BM, int BN, int KB, typename TOUT>
__global__ __launch_bounds__(256) void gemm_mfma_kernel(
    const unsigned short* __restrict__ X, const unsigned short* __restrict__ W,
    const float* __restrict__ bias, TOUT* __restrict__ Y,
    int N, int K, long ldx, long ldy)
{
    constexpr int WMT = (BM == 128 && BN == 128) ? 4 : 2;
    constexpr int WNT = (BM == 64 && BN == 64) ? 2 : 4;
    constexpr int CPR = KB / 8;                  // 16B chunks per row
    constexpr int CMSK = CPR - 1;
    constexpr int NCX = BM * CPR / 256;
    constexpr int NCW = BN * CPR / 256;
    __shared__ unsigned short Xs[BM * KB];       // also epilogue tile (32*BN fits)
    __shared__ unsigned short Ws[BN * KB];

    int tid = threadIdx.x;
    int wave = tid >> 6, lane = tid & 63;
    int quad = lane >> 4, l15 = lane & 15;
    int wmbase, wnbase;
    if (BM == 128 && BN == 128)      { wmbase = (wave & 1) * 64; wnbase = (wave >> 1) * 64; }
    else if (BM == 128 && BN == 64)  { wmbase = wave * 32;       wnbase = 0; }
    else                             { wmbase = (wave & 1) * 32; wnbase = (wave >> 1) * 32; }
    long m0 = (long)blockIdx.y * BM;
    int n0 = blockIdx.x * BN;

    floatx4 acc[WMT][WNT];
    #pragma unroll
    for (int i = 0; i < WMT; i++)
        #pragma unroll
        for (int j = 0; j < WNT; j++)
            acc[i][j] = (floatx4){0.f, 0.f, 0.f, 0.f};

    const unsigned short* Xb = X + m0 * ldx;
    const unsigned short* Wb = W + (long)n0 * K;

    for (int k0 = 0; k0 < K; k0 += KB) {
        #pragma unroll
        for (int j = 0; j < NCX; j++) {
            int s = (wave * NCX + j) * 64 + lane;
            int r = s / CPR, c = s % CPR;
            int cg = c ^ (r & CMSK);
            gload_lds16(&Xs[(wave * NCX + j) * 512],
                        Xb + (long)r * ldx + k0 + cg * 8);
        }
        #pragma unroll
        for (int j = 0; j < NCW; j++) {
            int s = (wave * NCW + j) * 64 + lane;
            int r = s / CPR, c = s % CPR;
            int cg = c ^ (r & CMSK);
            gload_lds16(&Ws[(wave * NCW + j) * 512],
                        Wb + (long)r * K + k0 + cg * 8);
        }
        __syncthreads();
        #pragma unroll
        for (int kk = 0; kk < KB; kk += 32) {
            short8 af[WMT], bfr[WNT];
            #pragma unroll
            for (int i = 0; i < WMT; i++) {
                int R = wmbase + i * 16 + l15;
                int cp = (kk / 8 + quad) ^ (R & CMSK);
                af[i] = *(short8*)&Xs[R * KB + cp * 8];
            }
            #pragma unroll
            for (int j = 0; j < WNT; j++) {
                int R = wnbase + j * 16 + l15;
                int cp = (kk / 8 + quad) ^ (R & CMSK);
                bfr[j] = *(short8*)&Ws[R * KB + cp * 8];
            }
            #pragma unroll
            for (int i = 0; i < WMT; i++)
                #pragma unroll
                for (int j = 0; j < WNT; j++)
                    acc[i][j] = __builtin_amdgcn_mfma_f32_16x16x32_bf16(
                        af[i], bfr[j], acc[i][j], 0, 0, 0);
        }
        __syncthreads();
    }

    if constexpr (sizeof(TOUT) == 2) {
        // bias preload (per-lane col for each j)
        float bv[WNT];
        #pragma unroll
        for (int j = 0; j < WNT; j++)
            bv[j] = bias ? bias[n0 + wnbase + j * 16 + l15] : 0.f;

        unsigned short* Es = Xs;                 // 32*BN <= BM*KB verified
        unsigned short* Yp = (unsigned short*)Y;
        constexpr int CH = BN / 8;
        #pragma unroll
        for (int g = 0; g < BM / 32; g++) {
            __syncthreads();
            #pragma unroll
            for (int i = 0; i < WMT; i++) {
                int rowbase = wmbase + i * 16;   // wave-uniform
                if ((rowbase >> 5) != g) continue;
                int lr = (rowbase & 31) + quad * 4;
                #pragma unroll
                for (int j = 0; j < WNT; j++) {
                    int nn = wnbase + j * 16 + l15;
                    #pragma unroll
                    for (int r = 0; r < 4; r++) {
                        float v = acc[i][j][r] + bv[j];
                        if (ACT == 1) v = tanhf(v);
                        else if (ACT == 3) v = (v > 0.f) ? v : expm1f(v);
                        else if (ACT == 4) v = (v > 20.f) ? v : __logf(1.0f + __expf(v));
                        Es[(lr + r) * BN + nn] = f2bf(v);
                    }
                }
            }
            __syncthreads();
            #pragma unroll
            for (int s0 = 0; s0 < 32 * CH; s0 += 256) {
                int s = s0 + tid;
                if (s < 32 * CH) {
                    int rr = s / CH, cb = (s % CH) * 8;
                    if (n0 + cb + 8 <= ldy)
                        *(ushort8*)(Yp + (m0 + g * 32 + rr) * ldy + n0 + cb) =
                            *(ushort8*)&Es[rr * BN + cb];
                }
            }
        }
    } else {
        #pragma unroll
        for (int i = 0; i < WMT; i++) {
            long mb = m0 + wmbase + i * 16 + quad * 4;
            #pragma unroll
            for (int j = 0; j < WNT; j++) {
                int n = n0 + wnbase + j * 16 + l15;
                if (n >= N) continue;
                float bvs = bias ? bias[n] : 0.f;
                #pragma unroll
                for (int r = 0; r < 4; r++) {
                    float v = acc[i][j][r] + bvs;
                    if (ACT == 1) v = tanhf(v);
                    else if (ACT == 3) v = (v > 0.f) ? v : expm1f(v);
                    else if (ACT == 4) v = (v > 20.f) ? v : __logf(1.0f + __expf(v));
                    Y[(mb + r) * ldy + n] = v;
                }
            }
        }
    }
}

// ---------------------------------------------------------------------------
// fused head, thread-per-output with pair-packed transposed bf16 weights.
// ---------------------------------------------------------------------------
__global__ __launch_bounds__(512) void head_kernel(
    const unsigned short* __restrict__ u,
    const unsigned short* __restrict__ w1t, const float* __restrict__ b1,
    const unsigned short* __restrict__ w2t, const float* __restrict__ b2,
    const float* __restrict__ w3, const float* __restrict__ b3,
    const float* __restrict__ sm, float* __restrict__ out)
{
    __shared__ float xs[DMV];
    __shared__ float h1s[512];
    __shared__ float red[8];
    int b = blockIdx.x;
    int tid = threadIdx.x;
    const unsigned short* xr = u + ((long)b * LSZ + (LSZ - 1)) * DMV;
    if (tid < DMV) xs[tid] = bf2f(xr[tid]);
    __syncthreads();

    float acc = 0.f;
    #pragma unroll 8
    for (int kk = 0; kk < DMV / 2; kk++) {
        unsigned wv = *(const unsigned*)&w1t[((long)kk * 512 + tid) * 2];
        acc = fmaf(xs[2 * kk],     bf2f((unsigned short)(wv & 0xffffu)), acc);
        acc = fmaf(xs[2 * kk + 1], bf2f((unsigned short)(wv >> 16)), acc);
    }
    h1s[tid] = fmaxf(acc + b1[tid], 0.f);
    __syncthreads();

    acc = 0.f;
    #pragma unroll 8
    for (int kk = 0; kk < 256; kk++) {
        unsigned wv = *(const unsigned*)&w2t[((long)kk * 512 + tid) * 2];
        acc = fmaf(h1s[2 * kk],     bf2f((unsigned short)(wv & 0xffffu)), acc);
        acc = fmaf(h1s[2 * kk + 1], bf2f((unsigned short)(wv >> 16)), acc);
    }
    float h2 = fmaxf(acc + b2[tid], 0.f);

    float part = h2 * w3[tid];
    #pragma unroll
    for (int off = 32; off > 0; off >>= 1) part += __shfl_xor(part, off, 64);
    if ((tid & 63) == 0) red[tid >> 6] = part;
    __syncthreads();
    if (tid == 0) {
        float s = b3[0];
        #pragma unroll
        for (int w = 0; w < 8; w++) s += red[w];
        float scale = sm[0] / 8.624618986159398f;   // 1 + ln(2048)
        out[b] = fmaxf(s * scale, 0.f);
    }
}

// ---------------------------------------------------------------------------
// depthwise causal conv (k=8) + bias + silu, sliding-window, bf16
// ---------------------------------------------------------------------------
#define TCONV 32
__global__ __launch_bounds__(256) void conv_kernel(
    const unsigned short* __restrict__ xz, const float* __restrict__ cw,
    const float* __restrict__ cb, unsigned short* __restrict__ xc)
{
    int d = blockIdx.x * 256 + threadIdx.x;
    int lb = blockIdx.z;
    int l0 = blockIdx.y * TCONV;
    long base = (long)lb * LSZ + l0;

    float w[8];
    #pragma unroll
    for (int k = 0; k < 8; k++) w[k] = cw[d * 8 + k];
    float bc = cb[d];

    float win[8];
    #pragma unroll
    for (int i = 0; i < 7; i++) {
        int l = l0 - 7 + i;
        win[i] = (l >= 0) ? bf2f(xz[(base - 7 + i) * 2560 + d]) : 0.f;
    }
    #pragma unroll
    for (int s = 0; s < TCONV; s++) {
        win[7] = bf2f(xz[(base + s) * 2560 + d]);
        float acc = bc;
        #pragma unroll
        for (int k = 0; k < 8; k++) acc = fmaf(win[k], w[k], acc);
        float sv = acc / (1.0f + __expf(-acc));
        xc[(base + s) * DIV + d] = f2bf(sv);
        #pragma unroll
        for (int k = 0; k < 7; k++) win[k] = win[k + 1];
    }
}

// power ladder: pw[n] = p^(n+1)
__device__ inline void pow_ladder(float p, float* pw) {
    pw[0] = p;
    pw[1] = pw[0] * pw[0];
    pw[2] = pw[1] * pw[0];
    pw[3] = pw[1] * pw[1];
    pw[4] = pw[3] * pw[0];
    pw[5] = pw[3] * pw[1];
    pw[6] = pw[3] * pw[2];
    pw[7] = pw[3] * pw[3];
    #pragma unroll
    for (int k = 8; k < 16; k++) pw[k] = pw[7] * pw[k - 8];
}

// ---------------------------------------------------------------------------
// Chunked scan phase 1: per-chunk local scan (h0=0), CLEN=32.
// ---------------------------------------------------------------------------
__global__ __launch_bounds__(256) void scan_local_kernel(
    const unsigned short* __restrict__ xc, unsigned short* xz,
    const unsigned short* __restrict__ dbc, const unsigned short* __restrict__ delta,
    const float* __restrict__ A_log, const float* __restrict__ Dp,
    unsigned short* __restrict__ hfin, float* __restrict__ sumd)
{
    __shared__ float S[CLEN * 32];
    int lb = blockIdx.z;
    int ch = blockIdx.y;
    int d = blockIdx.x * 256 + threadIdx.x;
    int tid = threadIdx.x;

    float a[NST], h[NST];
    #pragma unroll
    for (int n = 0; n < NST; n++) {
        a[n] = -__expf(A_log[d * NST + n]);
        h[n] = 0.f;
    }
    float a0 = a[0];
    bool geo = true;
    #pragma unroll
    for (int n = 1; n < NST; n++)
        geo = geo && (fabsf(a[n] - (float)(n + 1) * a0) <= 1e-4f * (float)(n + 1));
    float Dd = Dp[d];

    long tok0 = (long)lb * LSZ + ch * CLEN;
    for (int i = tid; i < CLEN * 32; i += 256) {
        int r = i >> 5, c = i & 31;
        S[i] = bf2f(dbc[(tok0 + r) * DBLD + 20 + c]);
    }
    __syncthreads();

    float sd = 0.f;
    if (__all(geo)) {
        for (int l = 0; l < CLEN; l++) {
            long m = tok0 + l;
            const float* row = &S[l * 32];
            float dl = bf2f(delta[m * DIV + d]);
            sd += dl;
            float xv = bf2f(xc[m * DIV + d]);
            float db = dl * xv;
            float pw[NST];
            pow_ladder(__expf(dl * a0), pw);
            float y = 0.f;
            #pragma unroll
            for (int n = 0; n < NST; n++) {
                h[n] = fmaf(pw[n], h[n], db * row[n]);
                y = fmaf(h[n], row[16 + n], y);
            }
            y = fmaf(xv, Dd, y);
            xz[m * 2560 + d] = f2bf(y);
        }
    } else {
        for (int l = 0; l < CLEN; l++) {
            long m = tok0 + l;
            const float* row = &S[l * 32];
            float dl = bf2f(delta[m * DIV + d]);
            sd += dl;
            float xv = bf2f(xc[m * DIV + d]);
            float db = dl * xv;
            float y = 0.f;
            #pragma unroll
            for (int n = 0; n < NST; n++) {
                float dA = __expf(dl * a[n]);
                h[n] = fmaf(dA, h[n], db * row[n]);
                y = fmaf(h[n], row[16 + n], y);
            }
            y = fmaf(xv, Dd, y);
            xz[m * 2560 + d] = f2bf(y);
        }
    }

    long cidx = ((long)lb * NCHUNK + ch) * DIV + d;
    #pragma unroll
    for (int n = 0; n < NST; n++) hfin[cidx * NST + n] = f2bf(h[n]);
    sumd[cidx] = sd;
}

// ---------------------------------------------------------------------------
// Phase 2: sequential prefix over chunks (bf16 hfin). One thread per (b,d,n).
// ---------------------------------------------------------------------------
__global__ __launch_bounds__(256) void scan_prefix_kernel(
    unsigned short* __restrict__ hfin, const float* __restrict__ sumd,
    const float* __restrict__ A_log, int Bc)
{
    long g = (long)blockIdx.x * 256 + threadIdx.x;
    int n = (int)(g & (NST - 1));
    long t = g >> 4;
    int d = (int)(t % DIV);
    int lb = (int)(t / DIV);
    if (lb >= Bc) return;

    float a = -__expf(A_log[d * NST + n]);
    float s = 0.f;
    for (int c = 0; c < NCHUNK; c++) {
        long cidx = ((long)lb * NCHUNK + c) * DIV + d;
        float hl = bf2f(hfin[cidx * NST + n]);
        float P = __expf(a * sumd[cidx]);
        hfin[cidx * NST + n] = f2bf(s);
        s = fmaf(P, s, hl);
    }
}

// ---------------------------------------------------------------------------
// Phase 3 (parallel over tokens; cheap serial cum recompute):
// y = y_local + C . (hin * exp(a*cum)), out = y * silu(z).
// ---------------------------------------------------------------------------
__global__ __launch_bounds__(256) void scan_fix_kernel(
    unsigned short* xz, const unsigned short* __restrict__ dbc,
    const unsigned short* __restrict__ delta,
    const float* __restrict__ A_log, const unsigned short* __restrict__ hfin)
{
    __shared__ float S[CLEN * 16];
    int lb = blockIdx.z;
    int ch = blockIdx.y;
    int d = blockIdx.x * 256 + threadIdx.x;
    int tid = threadIdx.x;

    float a[NST], hin[NST];
    #pragma unroll
    for (int n = 0; n < NST; n++) a[n] = -__expf(A_log[d * NST + n]);
    float a0 = a[0];
    bool geo = true;
    #pragma unroll
    for (int n = 1; n < NST; n++)
        geo = geo && (fabsf(a[n] - (float)(n + 1) * a0) <= 1e-4f * (float)(n + 1));

    long cidx = ((long)lb * NCHUNK + ch) * DIV + d;
    #pragma unroll
    for (int n = 0; n < NST; n++) hin[n] = bf2f(hfin[cidx * NST + n]);

    long tok0 = (long)lb * LSZ + ch * CLEN;
    for (int i = tid; i < CLEN * 16; i += 256) {
        int r = i >> 4, c = i & 15;
        S[i] = bf2f(dbc[(tok0 + r) * DBLD + 36 + c]);
    }
    __syncthreads();

    float cum = 0.f;
    if (__all(geo)) {
        for (int l = 0; l < CLEN; l++) {
            long m = tok0 + l;
            const float* row = &S[l * 16];
            cum += bf2f(delta[m * DIV + d]);
            float pw[NST];
            pow_ladder(__expf(cum * a0), pw);
            float fix = 0.f;
            #pragma unroll
            for (int n = 0; n < NST; n++)
                fix = fmaf(hin[n] * pw[n], row[n], fix);
            float y = bf2f(xz[m * 2560 + d]) + fix;
            float zv = bf2f(xz[m * 2560 + 1280 + d]);
            float sz = zv / (1.0f + __expf(-zv));
            xz[m * 2560 + d] = f2bf(y * sz);
        }
    } else {
        for (int l = 0; l < CLEN; l++) {
            long m = tok0 + l;
            const float* row = &S[l * 16];
            cum += bf2f(delta[m * DIV + d]);
            float fix = 0.f;
            #pragma unroll
            for (int n = 0; n < NST; n++)
                fix = fmaf(hin[n] * __expf(cum * a[n]), row[n], fix);
            float y = bf2f(xz[m * 2560 + d]) + fix;
            float zv = bf2f(xz[m * 2560 + 1280 + d]);
            float sz = zv / (1.0f + __expf(-zv));
            xz[m * 2560 + d] = f2bf(y * sz);
        }
    }
}

// ---------------------------------------------------------------------------
extern "C" void kernel_launch(void* const* d_in, const int* in_sizes, int n_in,
                              void* d_out, int out_size, void* d_ws, size_t ws_size,
                              hipStream_t stream) {
    const float* x        = (const float*)d_in[0];
    const float* fc_w     = (const float*)d_in[1];
    const float* fc_b     = (const float*)d_in[2];
    const float* lin_w    = (const float*)d_in[3];
    const float* lin_b    = (const float*)d_in[4];
    const float* inproj_w = (const float*)d_in[5];
    const float* conv_w   = (const float*)d_in[6];
    const float* conv_b   = (const float*)d_in[7];
    const float* xproj_w  = (const float*)d_in[8];
    const float* dtproj_w = (const float*)d_in[9];
    const float* dtproj_b = (const float*)d_in[10];
    const float* A_log    = (const float*)d_in[11];
    const float* Dp       = (const float*)d_in[12];
    const float* outproj_w= (const float*)d_in[13];
    const float* s1_w1    = (const float*)d_in[14];
    const float* s1_b1    = (const float*)d_in[15];
    const float* s1_w2    = (const float*)d_in[16];
    const float* s1_b2    = (const float*)d_in[17];
    const float* s1_w3    = (const float*)d_in[18];
    const float* s1_b3    = (const float*)d_in[19];

    const long NLIN = (long)NBLKV * DMV * DMV;
    const long NINP = (long)NBLKV * 2 * DIV * DMV;
    const long NXPP = (long)NBLKV * 64 * DIV;
    const long NOUT = (long)NBLKV * DMV * DIV;
    const long NDTW = (long)NBLKV * DIV * 32;
    const long NHW1 = (long)512 * DMV;
    const long NHW2 = (long)512 * 512;

    // ---- workspace sizing ----
    const long FIXED = 256 +
                       (NLIN + NINP + NXPP + NOUT + NDTW + NHW1 + NHW2) * 2 + 256;
    const long PER_BATCH = (long)LSZ * (DMV + DMV + 2 * DIV + DIV) * 2   // bf16 acts
                         + (long)LSZ * DBLD * 2                          // dbc bf16
                         + (long)LSZ * DIV * 2                           // delta bf16
                         + (long)NCHUNK * DIV * NST * 2                  // hfin bf16
                         + (long)NCHUNK * DIV * 4;                       // sumd
    int Bc = 8;
    while (Bc > 1 && (size_t)(FIXED + (long)Bc * PER_BATCH) > ws_size)
        Bc >>= 1;
    int nchunk_b = BSZ / Bc;
    long Mc = (long)Bc * LSZ;

    char* p = (char*)d_ws;
    float* sm = (float*)p;           p += 256;
    unsigned short* wlin = (unsigned short*)p; p += NLIN * 2;
    unsigned short* winp = (unsigned short*)p; p += NINP * 2;
    unsigned short* wxp  = (unsigned short*)p; p += NXPP * 2;
    unsigned short* wout = (unsigned short*)p; p += NOUT * 2;
    unsigned short* wdt  = (unsigned short*)p; p += NDTW * 2;
    unsigned short* w1t  = (unsigned short*)p; p += NHW1 * 2;
    unsigned short* w2t  = (unsigned short*)p; p += NHW2 * 2;
    unsigned short* u  = (unsigned short*)p;   p += Mc * DMV * 2;
    unsigned short* t  = (unsigned short*)p;   p += Mc * DMV * 2;
    unsigned short* xz = (unsigned short*)p;   p += Mc * 2560 * 2;
    unsigned short* xc = (unsigned short*)p;   p += Mc * DIV * 2;
    unsigned short* dbc = (unsigned short*)p;  p += Mc * DBLD * 2;
    unsigned short* delta = (unsigned short*)p; p += Mc * DIV * 2;
    unsigned short* hfin = (unsigned short*)p; p += (long)Bc * NCHUNK * DIV * NST * 2;
    float* sumd = (float*)p;

    // one-time (per launch) weight conversion
    convert_kernel<<<(unsigned)((NLIN / 4 + 255) / 256), 256, 0, stream>>>(lin_w, wlin, NLIN / 4);
    convert_kernel<<<(unsigned)((NINP / 4 + 255) / 256), 256, 0, stream>>>(inproj_w, winp, NINP / 4);
    convert_kernel<<<(unsigned)((NOUT / 4 + 255) / 256), 256, 0, stream>>>(outproj_w, wout, NOUT / 4);
    convert_xp_kernel<<<(unsigned)((NXPP + 255) / 256), 256, 0, stream>>>(xproj_w, wxp);
    convert_dtw_kernel<<<(unsigned)((NDTW + 255) / 256), 256, 0, stream>>>(dtproj_w, wdt);
    convert_t2_kernel<<<(unsigned)((NHW1 + 255) / 256), 256, 0, stream>>>(s1_w1, w1t, 512, DMV);
    convert_t2_kernel<<<(unsigned)((NHW2 + 255) / 256), 256, 0, stream>>>(s1_w2, w2t, 512, 512);

    init_sm_kernel<<<1, 64, 0, stream>>>(sm);
    reduce_max_kernel<<<32, 256, 0, stream>>>(x, sm);

    for (int c = 0; c < nchunk_b; c++) {
        int b0 = c * Bc;
        fc_kernel<<<dim3(5, (unsigned)(Mc / 4)), 256, 0, stream>>>(
            x + (long)b0 * LSZ * 4, fc_w, fc_b, sm, u);

        for (int i = 0; i < NBLKV; i++) {
            const float* lb  = lin_b    + (long)i * DMV;
            const float* cw  = conv_w   + (long)i * DIV * DCV;
            const float* cb  = conv_b   + (long)i * DIV;
            const float* dpb = dtproj_b + (long)i * DIV;
            const float* al  = A_log    + (long)i * DIV * NST;
            const float* dd  = Dp       + (long)i * DIV;

            // lin + tanh: (Mc x320)@(320x320)^T -> t (bf16)
            gemm_mfma_kernel<1, 128, 64, 64, unsigned short>
                <<<dim3(5, (unsigned)(Mc / 128)), 256, 0, stream>>>(
                u, wlin + (long)i * DMV * DMV, lb, t, DMV, DMV, DMV, DMV);
            // inproj: (Mc x320)@(2560x320)^T -> xz (bf16)
            gemm_mfma_kernel<0, 128, 128, 64, unsigned short>
                <<<dim3(20, (unsigned)(Mc / 128)), 256, 0, stream>>>(
                t, winp + (long)i * 2 * DIV * DMV, nullptr, xz, 2 * DIV, DMV, DMV, 2 * DIV);
            // conv + silu (sliding window, bf16)
            conv_kernel<<<dim3(5, LSZ / TCONV, Bc), 256, 0, stream>>>(xz, cw, cb, xc);
            // xproj: (Mc x1280)@(64x1280)^T (padded W) -> dbc (bf16, ld 56)
            gemm_mfma_kernel<0, 64, 64, 64, unsigned short>
                <<<dim3(1, (unsigned)(Mc / 64)), 256, 0, stream>>>(
                xc, wxp + (long)i * 64 * DIV, nullptr, dbc,
                DTR + 2 * NST, DIV, DIV, DBLD);
            // delta = softplus(dbc[:, :20] @ dtw^T + b): K padded to 32, bf16 out
            gemm_mfma_kernel<4, 128, 128, 32, unsigned short>
                <<<dim3(10, (unsigned)(Mc / 128)), 256, 0, stream>>>(
                dbc, wdt + (long)i * DIV * 32, dpb, delta, DIV, 32, DBLD, DIV);
            // chunked scan (CLEN=32, NCHUNK=64)
            scan_local_kernel<<<dim3(5, NCHUNK, Bc), 256, 0, stream>>>(
                xc, xz, dbc, delta, al, dd, hfin, sumd);
            scan_prefix_kernel<<<dim3(Bc * 80), 256, 0, stream>>>(hfin, sumd, al, Bc);
            scan_fix_kernel<<<dim3(5, NCHUNK, Bc), 256, 0, stream>>>(
                xz, dbc, delta, al, hfin);
            // outproj + elu: (Mc x1280)@(320x1280)^T -> u (bf16)
            gemm_mfma_kernel<3, 128, 64, 64, unsigned short>
                <<<dim3(5, (unsigned)(Mc / 128)), 256, 0, stream>>>(
                xz, wout + (long)i * DMV * DIV, nullptr, u, DMV, DIV, 2 * DIV, DMV);
        }

        // fused head on last token of each batch in chunk
        head_kernel<<<Bc, 512, 0, stream>>>(u, w1t, s1_b1, w2t, s1_b2,
                                            s1_w3, s1_b3, sm, (float*)d_out + b0);
    }
}

// Round 13
// 1303.239 us; speedup vs baseline: 1.0291x; 1.0291x over previous
//
#include <hip/hip_runtime.h>
#include <math.h>

// Problem constants
#define BSZ 8
#define LSZ 2048
#define DMV 320
#define DIV 1280
#define NST 16
#define DCV 8
#define DTR 20
#define NBLKV 4
#define MTOT (BSZ*LSZ)   // 16384
#define NCHUNK 128
#define CLEN 16          // NCHUNK*CLEN == LSZ
#define DBLD 56          // dbc leading dim (bf16), 16B-aligned rows

typedef __attribute__((ext_vector_type(8))) short short8;
typedef __attribute__((ext_vector_type(8))) unsigned short ushort8;
typedef __attribute__((ext_vector_type(4))) float floatx4;

__device__ inline unsigned short f2bf(float f) {
    union { float f; unsigned u; } v; v.f = f;
    unsigned r = v.u + 0x7FFFu + ((v.u >> 16) & 1u);
    return (unsigned short)(r >> 16);
}
__device__ inline float bf2f(unsigned short b) {
    union { unsigned u; float f; } v; v.u = ((unsigned)b) << 16;
    return v.f;
}

// async 16B global -> LDS (wave-uniform LDS base + lane*16) [m97 pattern]
__device__ __forceinline__ void gload_lds16(unsigned short* l, const unsigned short* g) {
    __builtin_amdgcn_global_load_lds(
        (const __attribute__((address_space(1))) unsigned int*)g,
        (__attribute__((address_space(3))) unsigned int*)l, 16, 0, 0);
}

// ---------------------------------------------------------------------------
// fp32 -> bf16 weight conversion (grid-stride, n % 4 == 0)
// ---------------------------------------------------------------------------
__global__ __launch_bounds__(256) void convert_kernel(
    const float* __restrict__ src, unsigned short* __restrict__ dst, long n4) {
    long i = (long)blockIdx.x * 256 + threadIdx.x;
    if (i >= n4) return;
    float4 v = *(const float4*)(src + i * 4);
    unsigned short o[4] = {f2bf(v.x), f2bf(v.y), f2bf(v.z), f2bf(v.w)};
    *(unsigned long long*)(dst + i * 4) = *(unsigned long long*)o;
}

// dtproj_w (NBLKV x 1280 x 20) -> bf16 padded (NBLKV x 1280 x 32), zero cols 20..31
__global__ __launch_bounds__(256) void convert_dtw_kernel(
    const float* __restrict__ src, unsigned short* __restrict__ dst) {
    int i = blockIdx.x * 256 + threadIdx.x;
    if (i >= NBLKV * DIV * 32) return;
    int l = i / (DIV * 32), rem = i % (DIV * 32);
    int d = rem >> 5, j = rem & 31;
    dst[i] = (j < DTR) ? f2bf(src[((long)l * DIV + d) * DTR + j]) : (unsigned short)0;
}

// xproj_w (NBLKV x 52 x 1280) -> bf16 padded (NBLKV x 64 x 1280), zero rows 52..63
__global__ __launch_bounds__(256) void convert_xp_kernel(
    const float* __restrict__ src, unsigned short* __restrict__ dst) {
    int i = blockIdx.x * 256 + threadIdx.x;
    if (i >= NBLKV * 64 * DIV) return;
    int l = i / (64 * DIV), rem = i % (64 * DIV);
    int n = rem / DIV, k = rem % DIV;
    dst[i] = (n < DTR + 2 * NST) ? f2bf(src[((long)l * (DTR + 2 * NST) + n) * DIV + k])
                                 : (unsigned short)0;
}

// head weight (N x K) fp32 -> pair-packed transposed bf16
__global__ __launch_bounds__(256) void convert_t2_kernel(
    const float* __restrict__ src, unsigned short* __restrict__ dst, int N, int K) {
    int i = blockIdx.x * 256 + threadIdx.x;
    if (i >= N * K) return;
    int n = i / K, k = i % K;
    dst[((k >> 1) * N + n) * 2 + (k & 1)] = f2bf(src[i]);
}

// ---------------------------------------------------------------------------
// start_max reduction (x[:,:,2] >= 0, so int-compare atomicMax is valid)
// ---------------------------------------------------------------------------
__global__ void init_sm_kernel(float* sm) {
    if (threadIdx.x == 0) ((int*)sm)[0] = 0;
}

__global__ void reduce_max_kernel(const float* __restrict__ x, float* sm) {
    int idx = blockIdx.x * blockDim.x + threadIdx.x;
    float v = 0.f;
    for (int i = idx; i < MTOT; i += gridDim.x * blockDim.x)
        v = fmaxf(v, x[i * 4 + 2]);
    #pragma unroll
    for (int off = 32; off > 0; off >>= 1)
        v = fmaxf(v, __shfl_xor(v, off, 64));
    if ((threadIdx.x & 63) == 0)
        atomicMax((int*)sm, __float_as_int(v));
}

// ---------------------------------------------------------------------------
// input normalize + fc (K=4) -> bf16 u
// ---------------------------------------------------------------------------
__global__ __launch_bounds__(256) void fc_kernel(
    const float* __restrict__ x, const float* __restrict__ fw,
    const float* __restrict__ fb, const float* __restrict__ sm,
    unsigned short* __restrict__ u) {
    int o = blockIdx.x * 64 + (threadIdx.x & 63);
    long m = (long)blockIdx.y * 4 + (threadIdx.x >> 6);
    float inv_sm = 1.0f / sm[0];
    float x0 = x[m * 4 + 0] * (1.0f / 255.0f);
    float x1 = x[m * 4 + 1] * (1.0f / 255.0f);
    float x2 = x[m * 4 + 2] * inv_sm;
    float x3 = x[m * 4 + 3];
    float acc = fb[o];
    acc = fmaf(x0, fw[o * 4 + 0], acc);
    acc = fmaf(x1, fw[o * 4 + 1], acc);
    acc = fmaf(x2, fw[o * 4 + 2], acc);
    acc = fmaf(x3, fw[o * 4 + 3], acc);
    u[m * DMV + o] = f2bf(acc);
}

// ---------------------------------------------------------------------------
// bf16 MFMA GEMM with async global->LDS staging + XOR chunk swizzle
// (direct-store epilogue — R11 version; LDS-transpose epilogue regressed)
// ---------------------------------------------------------------------------
template<int ACT, int BM, int BN, int KB, typename TOUT>
__global__ __launch_bounds__(256) void gemm_mfma_kernel(
    const unsigned short* __restrict__ X, const unsigned short* __restrict__ W,
    const float* __restrict__ bias, TOUT* __restrict__ Y,
    int N, int K, long ldx, long ldy)
{
    constexpr int WMT = (BM == 128 && BN == 128) ? 4 : 2;
    constexpr int WNT = (BM == 64 && BN == 64) ? 2 : 4;
    constexpr int CPR = KB / 8;                  // 16B chunks per row
    constexpr int CMSK = CPR - 1;
    constexpr int NCX = BM * CPR / 256;
    constexpr int NCW = BN * CPR / 256;
    __shared__ unsigned short Xs[BM * KB];
    __shared__ unsigned short Ws[BN * KB];

    int tid = threadIdx.x;
    int wave = tid >> 6, lane = tid & 63;
    int quad = lane >> 4, l15 = lane & 15;
    int wmbase, wnbase;
    if (BM == 128 && BN == 128)      { wmbase = (wave & 1) * 64; wnbase = (wave >> 1) * 64; }
    else if (BM == 128 && BN == 64)  { wmbase = wave * 32;       wnbase = 0; }
    else                             { wmbase = (wave & 1) * 32; wnbase = (wave >> 1) * 32; }
    long m0 = (long)blockIdx.y * BM;
    int n0 = blockIdx.x * BN;

    floatx4 acc[WMT][WNT];
    #pragma unroll
    for (int i = 0; i < WMT; i++)
        #pragma unroll
        for (int j = 0; j < WNT; j++)
            acc[i][j] = (floatx4){0.f, 0.f, 0.f, 0.f};

    const unsigned short* Xb = X + m0 * ldx;
    const unsigned short* Wb = W + (long)n0 * K;

    for (int k0 = 0; k0 < K; k0 += KB) {
        #pragma unroll
        for (int j = 0; j < NCX; j++) {
            int s = (wave * NCX + j) * 64 + lane;
            int r = s / CPR, c = s % CPR;
            int cg = c ^ (r & CMSK);
            gload_lds16(&Xs[(wave * NCX + j) * 512],
                        Xb + (long)r * ldx + k0 + cg * 8);
        }
        #pragma unroll
        for (int j = 0; j < NCW; j++) {
            int s = (wave * NCW + j) * 64 + lane;
            int r = s / CPR, c = s % CPR;
            int cg = c ^ (r & CMSK);
            gload_lds16(&Ws[(wave * NCW + j) * 512],
                        Wb + (long)r * K + k0 + cg * 8);
        }
        __syncthreads();
        #pragma unroll
        for (int kk = 0; kk < KB; kk += 32) {
            short8 af[WMT], bfr[WNT];
            #pragma unroll
            for (int i = 0; i < WMT; i++) {
                int R = wmbase + i * 16 + l15;
                int cp = (kk / 8 + quad) ^ (R & CMSK);
                af[i] = *(short8*)&Xs[R * KB + cp * 8];
            }
            #pragma unroll
            for (int j = 0; j < WNT; j++) {
                int R = wnbase + j * 16 + l15;
                int cp = (kk / 8 + quad) ^ (R & CMSK);
                bfr[j] = *(short8*)&Ws[R * KB + cp * 8];
            }
            #pragma unroll
            for (int i = 0; i < WMT; i++)
                #pragma unroll
                for (int j = 0; j < WNT; j++)
                    acc[i][j] = __builtin_amdgcn_mfma_f32_16x16x32_bf16(
                        af[i], bfr[j], acc[i][j], 0, 0, 0);
        }
        __syncthreads();
    }

    #pragma unroll
    for (int i = 0; i < WMT; i++) {
        long mb = m0 + wmbase + i * 16 + quad * 4;
        #pragma unroll
        for (int j = 0; j < WNT; j++) {
            int n = n0 + wnbase + j * 16 + l15;
            if (n >= N) continue;
            float bv = bias ? bias[n] : 0.f;
            #pragma unroll
            for (int r = 0; r < 4; r++) {
                float v = acc[i][j][r] + bv;
                if (ACT == 1) v = tanhf(v);
                else if (ACT == 3) v = (v > 0.f) ? v : expm1f(v);
                else if (ACT == 4) v = (v > 20.f) ? v : __logf(1.0f + __expf(v));
                if constexpr (sizeof(TOUT) == 2)
                    Y[(mb + r) * ldy + n] = f2bf(v);
                else
                    Y[(mb + r) * ldy + n] = v;
            }
        }
    }
}

// ---------------------------------------------------------------------------
// fused head, thread-per-output with pair-packed transposed bf16 weights.
// ---------------------------------------------------------------------------
__global__ __launch_bounds__(512) void head_kernel(
    const unsigned short* __restrict__ u,
    const unsigned short* __restrict__ w1t, const float* __restrict__ b1,
    const unsigned short* __restrict__ w2t, const float* __restrict__ b2,
    const float* __restrict__ w3, const float* __restrict__ b3,
    const float* __restrict__ sm, float* __restrict__ out)
{
    __shared__ float xs[DMV];
    __shared__ float h1s[512];
    __shared__ float red[8];
    int b = blockIdx.x;
    int tid = threadIdx.x;
    const unsigned short* xr = u + ((long)b * LSZ + (LSZ - 1)) * DMV;
    if (tid < DMV) xs[tid] = bf2f(xr[tid]);
    __syncthreads();

    float acc = 0.f;
    #pragma unroll 8
    for (int kk = 0; kk < DMV / 2; kk++) {
        unsigned wv = *(const unsigned*)&w1t[((long)kk * 512 + tid) * 2];
        acc = fmaf(xs[2 * kk],     bf2f((unsigned short)(wv & 0xffffu)), acc);
        acc = fmaf(xs[2 * kk + 1], bf2f((unsigned short)(wv >> 16)), acc);
    }
    h1s[tid] = fmaxf(acc + b1[tid], 0.f);
    __syncthreads();

    acc = 0.f;
    #pragma unroll 8
    for (int kk = 0; kk < 256; kk++) {
        unsigned wv = *(const unsigned*)&w2t[((long)kk * 512 + tid) * 2];
        acc = fmaf(h1s[2 * kk],     bf2f((unsigned short)(wv & 0xffffu)), acc);
        acc = fmaf(h1s[2 * kk + 1], bf2f((unsigned short)(wv >> 16)), acc);
    }
    float h2 = fmaxf(acc + b2[tid], 0.f);

    float part = h2 * w3[tid];
    #pragma unroll
    for (int off = 32; off > 0; off >>= 1) part += __shfl_xor(part, off, 64);
    if ((tid & 63) == 0) red[tid >> 6] = part;
    __syncthreads();
    if (tid == 0) {
        float s = b3[0];
        #pragma unroll
        for (int w = 0; w < 8; w++) s += red[w];
        float scale = sm[0] / 8.624618986159398f;   // 1 + ln(2048)
        out[b] = fmaxf(s * scale, 0.f);
    }
}

// ---------------------------------------------------------------------------
// depthwise causal conv (k=8) + bias + silu, sliding-window, bf16
// ---------------------------------------------------------------------------
#define TCONV 32
__global__ __launch_bounds__(256) void conv_kernel(
    const unsigned short* __restrict__ xz, const float* __restrict__ cw,
    const float* __restrict__ cb, unsigned short* __restrict__ xc)
{
    int d = blockIdx.x * 256 + threadIdx.x;
    int lb = blockIdx.z;
    int l0 = blockIdx.y * TCONV;
    long base = (long)lb * LSZ + l0;

    float w[8];
    #pragma unroll
    for (int k = 0; k < 8; k++) w[k] = cw[d * 8 + k];
    float bc = cb[d];

    float win[8];
    #pragma unroll
    for (int i = 0; i < 7; i++) {
        int l = l0 - 7 + i;
        win[i] = (l >= 0) ? bf2f(xz[(base - 7 + i) * 2560 + d]) : 0.f;
    }
    #pragma unroll
    for (int s = 0; s < TCONV; s++) {
        win[7] = bf2f(xz[(base + s) * 2560 + d]);
        float acc = bc;
        #pragma unroll
        for (int k = 0; k < 8; k++) acc = fmaf(win[k], w[k], acc);
        float sv = acc / (1.0f + __expf(-acc));
        xc[(base + s) * DIV + d] = f2bf(sv);
        #pragma unroll
        for (int k = 0; k < 7; k++) win[k] = win[k + 1];
    }
}

// power ladder: pw[n] = p^(n+1)
__device__ inline void pow_ladder(float p, float* pw) {
    pw[0] = p;
    pw[1] = pw[0] * pw[0];
    pw[2] = pw[1] * pw[0];
    pw[3] = pw[1] * pw[1];
    pw[4] = pw[3] * pw[0];
    pw[5] = pw[3] * pw[1];
    pw[6] = pw[3] * pw[2];
    pw[7] = pw[3] * pw[3];
    #pragma unroll
    for (int k = 8; k < 16; k++) pw[k] = pw[7] * pw[k - 8];
}

// ---------------------------------------------------------------------------
// Chunked scan phase 1: per-chunk local scan (h0=0), CLEN=16.
// ---------------------------------------------------------------------------
__global__ __launch_bounds__(256) void scan_local_kernel(
    const unsigned short* __restrict__ xc, unsigned short* xz,
    const unsigned short* __restrict__ dbc, const unsigned short* __restrict__ delta,
    const float* __restrict__ A_log, const float* __restrict__ Dp,
    unsigned short* __restrict__ hfin, float* __restrict__ sumd)
{
    __shared__ float S[CLEN * 32];
    int lb = blockIdx.z;
    int ch = blockIdx.y;
    int d = blockIdx.x * 256 + threadIdx.x;
    int tid = threadIdx.x;

    float a[NST], h[NST];
    #pragma unroll
    for (int n = 0; n < NST; n++) {
        a[n] = -__expf(A_log[d * NST + n]);
        h[n] = 0.f;
    }
    float a0 = a[0];
    bool geo = true;
    #pragma unroll
    for (int n = 1; n < NST; n++)
        geo = geo && (fabsf(a[n] - (float)(n + 1) * a0) <= 1e-4f * (float)(n + 1));
    float Dd = Dp[d];

    long tok0 = (long)lb * LSZ + ch * CLEN;
    for (int i = tid; i < CLEN * 32; i += 256) {
        int r = i >> 5, c = i & 31;
        S[i] = bf2f(dbc[(tok0 + r) * DBLD + 20 + c]);
    }
    __syncthreads();

    float sd = 0.f;
    if (__all(geo)) {
        for (int l = 0; l < CLEN; l++) {
            long m = tok0 + l;
            const float* row = &S[l * 32];
            float dl = bf2f(delta[m * DIV + d]);
            sd += dl;
            float xv = bf2f(xc[m * DIV + d]);
            float db = dl * xv;
            float pw[NST];
            pow_ladder(__expf(dl * a0), pw);
            float y = 0.f;
            #pragma unroll
            for (int n = 0; n < NST; n++) {
                h[n] = fmaf(pw[n], h[n], db * row[n]);
                y = fmaf(h[n], row[16 + n], y);
            }
            y = fmaf(xv, Dd, y);
            xz[m * 2560 + d] = f2bf(y);
        }
    } else {
        for (int l = 0; l < CLEN; l++) {
            long m = tok0 + l;
            const float* row = &S[l * 32];
            float dl = bf2f(delta[m * DIV + d]);
            sd += dl;
            float xv = bf2f(xc[m * DIV + d]);
            float db = dl * xv;
            float y = 0.f;
            #pragma unroll
            for (int n = 0; n < NST; n++) {
                float dA = __expf(dl * a[n]);
                h[n] = fmaf(dA, h[n], db * row[n]);
                y = fmaf(h[n], row[16 + n], y);
            }
            y = fmaf(xv, Dd, y);
            xz[m * 2560 + d] = f2bf(y);
        }
    }

    long cidx = ((long)lb * NCHUNK + ch) * DIV + d;
    #pragma unroll
    for (int n = 0; n < NST; n++) hfin[cidx * NST + n] = f2bf(h[n]);
    sumd[cidx] = sd;
}

// ---------------------------------------------------------------------------
// Phase 2: sequential prefix over chunks (bf16 hfin). One thread per (b,d,n).
// ---------------------------------------------------------------------------
__global__ __launch_bounds__(256) void scan_prefix_kernel(
    unsigned short* __restrict__ hfin, const float* __restrict__ sumd,
    const float* __restrict__ A_log, int Bc)
{
    long g = (long)blockIdx.x * 256 + threadIdx.x;
    int n = (int)(g & (NST - 1));
    long t = g >> 4;
    int d = (int)(t % DIV);
    int lb = (int)(t / DIV);
    if (lb >= Bc) return;

    float a = -__expf(A_log[d * NST + n]);
    float s = 0.f;
    for (int c = 0; c < NCHUNK; c++) {
        long cidx = ((long)lb * NCHUNK + c) * DIV + d;
        float hl = bf2f(hfin[cidx * NST + n]);
        float P = __expf(a * sumd[cidx]);
        hfin[cidx * NST + n] = f2bf(s);
        s = fmaf(P, s, hl);
    }
}

// ---------------------------------------------------------------------------
// Phase 3 (parallel over tokens; cheap serial cum recompute):
// y = y_local + C . (hin * exp(a*cum)), out = y * silu(z).
// ---------------------------------------------------------------------------
__global__ __launch_bounds__(256) void scan_fix_kernel(
    unsigned short* xz, const unsigned short* __restrict__ dbc,
    const unsigned short* __restrict__ delta,
    const float* __restrict__ A_log, const unsigned short* __restrict__ hfin)
{
    __shared__ float S[CLEN * 16];
    int lb = blockIdx.z;
    int ch = blockIdx.y;
    int d = blockIdx.x * 256 + threadIdx.x;
    int tid = threadIdx.x;

    float a[NST], hin[NST];
    #pragma unroll
    for (int n = 0; n < NST; n++) a[n] = -__expf(A_log[d * NST + n]);
    float a0 = a[0];
    bool geo = true;
    #pragma unroll
    for (int n = 1; n < NST; n++)
        geo = geo && (fabsf(a[n] - (float)(n + 1) * a0) <= 1e-4f * (float)(n + 1));

    long cidx = ((long)lb * NCHUNK + ch) * DIV + d;
    #pragma unroll
    for (int n = 0; n < NST; n++) hin[n] = bf2f(hfin[cidx * NST + n]);

    long tok0 = (long)lb * LSZ + ch * CLEN;
    for (int i = tid; i < CLEN * 16; i += 256) {
        int r = i >> 4, c = i & 15;
        S[i] = bf2f(dbc[(tok0 + r) * DBLD + 36 + c]);
    }
    __syncthreads();

    float cum = 0.f;
    if (__all(geo)) {
        for (int l = 0; l < CLEN; l++) {
            long m = tok0 + l;
            const float* row = &S[l * 16];
            cum += bf2f(delta[m * DIV + d]);
            float pw[NST];
            pow_ladder(__expf(cum * a0), pw);
            float fix = 0.f;
            #pragma unroll
            for (int n = 0; n < NST; n++)
                fix = fmaf(hin[n] * pw[n], row[n], fix);
            float y = bf2f(xz[m * 2560 + d]) + fix;
            float zv = bf2f(xz[m * 2560 + 1280 + d]);
            float sz = zv / (1.0f + __expf(-zv));
            xz[m * 2560 + d] = f2bf(y * sz);
        }
    } else {
        for (int l = 0; l < CLEN; l++) {
            long m = tok0 + l;
            const float* row = &S[l * 16];
            cum += bf2f(delta[m * DIV + d]);
            float fix = 0.f;
            #pragma unroll
            for (int n = 0; n < NST; n++)
                fix = fmaf(hin[n] * __expf(cum * a[n]), row[n], fix);
            float y = bf2f(xz[m * 2560 + d]) + fix;
            float zv = bf2f(xz[m * 2560 + 1280 + d]);
            float sz = zv / (1.0f + __expf(-zv));
            xz[m * 2560 + d] = f2bf(y * sz);
        }
    }
}

// ---------------------------------------------------------------------------
extern "C" void kernel_launch(void* const* d_in, const int* in_sizes, int n_in,
                              void* d_out, int out_size, void* d_ws, size_t ws_size,
                              hipStream_t stream) {
    const float* x        = (const float*)d_in[0];
    const float* fc_w     = (const float*)d_in[1];
    const float* fc_b     = (const float*)d_in[2];
    const float* lin_w    = (const float*)d_in[3];
    const float* lin_b    = (const float*)d_in[4];
    const float* inproj_w = (const float*)d_in[5];
    const float* conv_w   = (const float*)d_in[6];
    const float* conv_b   = (const float*)d_in[7];
    const float* xproj_w  = (const float*)d_in[8];
    const float* dtproj_w = (const float*)d_in[9];
    const float* dtproj_b = (const float*)d_in[10];
    const float* A_log    = (const float*)d_in[11];
    const float* Dp       = (const float*)d_in[12];
    const float* outproj_w= (const float*)d_in[13];
    const float* s1_w1    = (const float*)d_in[14];
    const float* s1_b1    = (const float*)d_in[15];
    const float* s1_w2    = (const float*)d_in[16];
    const float* s1_b2    = (const float*)d_in[17];
    const float* s1_w3    = (const float*)d_in[18];
    const float* s1_b3    = (const float*)d_in[19];

    const long NLIN = (long)NBLKV * DMV * DMV;
    const long NINP = (long)NBLKV * 2 * DIV * DMV;
    const long NXPP = (long)NBLKV * 64 * DIV;
    const long NOUT = (long)NBLKV * DMV * DIV;
    const long NDTW = (long)NBLKV * DIV * 32;
    const long NHW1 = (long)512 * DMV;
    const long NHW2 = (long)512 * 512;

    // ---- workspace sizing ----
    const long FIXED = 256 +
                       (NLIN + NINP + NXPP + NOUT + NDTW + NHW1 + NHW2) * 2 + 256;
    const long PER_BATCH = (long)LSZ * (DMV + DMV + 2 * DIV + DIV) * 2   // bf16 acts
                         + (long)LSZ * DBLD * 2                          // dbc bf16
                         + (long)LSZ * DIV * 2                           // delta bf16
                         + (long)NCHUNK * DIV * NST * 2                  // hfin bf16
                         + (long)NCHUNK * DIV * 4;                       // sumd
    int Bc = 8;
    while (Bc > 1 && (size_t)(FIXED + (long)Bc * PER_BATCH) > ws_size)
        Bc >>= 1;
    int nchunk_b = BSZ / Bc;
    long Mc = (long)Bc * LSZ;

    char* p = (char*)d_ws;
    float* sm = (float*)p;           p += 256;
    unsigned short* wlin = (unsigned short*)p; p += NLIN * 2;
    unsigned short* winp = (unsigned short*)p; p += NINP * 2;
    unsigned short* wxp  = (unsigned short*)p; p += NXPP * 2;
    unsigned short* wout = (unsigned short*)p; p += NOUT * 2;
    unsigned short* wdt  = (unsigned short*)p; p += NDTW * 2;
    unsigned short* w1t  = (unsigned short*)p; p += NHW1 * 2;
    unsigned short* w2t  = (unsigned short*)p; p += NHW2 * 2;
    unsigned short* u  = (unsigned short*)p;   p += Mc * DMV * 2;
    unsigned short* t  = (unsigned short*)p;   p += Mc * DMV * 2;
    unsigned short* xz = (unsigned short*)p;   p += Mc * 2560 * 2;
    unsigned short* xc = (unsigned short*)p;   p += Mc * DIV * 2;
    unsigned short* dbc = (unsigned short*)p;  p += Mc * DBLD * 2;
    unsigned short* delta = (unsigned short*)p; p += Mc * DIV * 2;
    unsigned short* hfin = (unsigned short*)p; p += (long)Bc * NCHUNK * DIV * NST * 2;
    float* sumd = (float*)p;

    // one-time (per launch) weight conversion
    convert_kernel<<<(unsigned)((NLIN / 4 + 255) / 256), 256, 0, stream>>>(lin_w, wlin, NLIN / 4);
    convert_kernel<<<(unsigned)((NINP / 4 + 255) / 256), 256, 0, stream>>>(inproj_w, winp, NINP / 4);
    convert_kernel<<<(unsigned)((NOUT / 4 + 255) / 256), 256, 0, stream>>>(outproj_w, wout, NOUT / 4);
    convert_xp_kernel<<<(unsigned)((NXPP + 255) / 256), 256, 0, stream>>>(xproj_w, wxp);
    convert_dtw_kernel<<<(unsigned)((NDTW + 255) / 256), 256, 0, stream>>>(dtproj_w, wdt);
    convert_t2_kernel<<<(unsigned)((NHW1 + 255) / 256), 256, 0, stream>>>(s1_w1, w1t, 512, DMV);
    convert_t2_kernel<<<(unsigned)((NHW2 + 255) / 256), 256, 0, stream>>>(s1_w2, w2t, 512, 512);

    init_sm_kernel<<<1, 64, 0, stream>>>(sm);
    reduce_max_kernel<<<32, 256, 0, stream>>>(x, sm);

    for (int c = 0; c < nchunk_b; c++) {
        int b0 = c * Bc;
        fc_kernel<<<dim3(5, (unsigned)(Mc / 4)), 256, 0, stream>>>(
            x + (long)b0 * LSZ * 4, fc_w, fc_b, sm, u);

        for (int i = 0; i < NBLKV; i++) {
            const float* lb  = lin_b    + (long)i * DMV;
            const float* cw  = conv_w   + (long)i * DIV * DCV;
            const float* cb  = conv_b   + (long)i * DIV;
            const float* dpb = dtproj_b + (long)i * DIV;
            const float* al  = A_log    + (long)i * DIV * NST;
            const float* dd  = Dp       + (long)i * DIV;

            // lin + tanh: (Mc x320)@(320x320)^T -> t (bf16)
            gemm_mfma_kernel<1, 128, 64, 64, unsigned short>
                <<<dim3(5, (unsigned)(Mc / 128)), 256, 0, stream>>>(
                u, wlin + (long)i * DMV * DMV, lb, t, DMV, DMV, DMV, DMV);
            // inproj: (Mc x320)@(2560x320)^T -> xz (bf16)
            gemm_mfma_kernel<0, 128, 128, 64, unsigned short>
                <<<dim3(20, (unsigned)(Mc / 128)), 256, 0, stream>>>(
                t, winp + (long)i * 2 * DIV * DMV, nullptr, xz, 2 * DIV, DMV, DMV, 2 * DIV);
            // conv + silu (sliding window, bf16)
            conv_kernel<<<dim3(5, LSZ / TCONV, Bc), 256, 0, stream>>>(xz, cw, cb, xc);
            // xproj: (Mc x1280)@(64x1280)^T (padded W) -> dbc (bf16, ld 56)
            gemm_mfma_kernel<0, 64, 64, 64, unsigned short>
                <<<dim3(1, (unsigned)(Mc / 64)), 256, 0, stream>>>(
                xc, wxp + (long)i * 64 * DIV, nullptr, dbc,
                DTR + 2 * NST, DIV, DIV, DBLD);
            // delta = softplus(dbc[:, :20] @ dtw^T + b): K padded to 32, bf16 out
            gemm_mfma_kernel<4, 128, 128, 32, unsigned short>
                <<<dim3(10, (unsigned)(Mc / 128)), 256, 0, stream>>>(
                dbc, wdt + (long)i * DIV * 32, dpb, delta, DIV, 32, DBLD, DIV);
            // chunked scan (CLEN=16, NCHUNK=128)
            scan_local_kernel<<<dim3(5, NCHUNK, Bc), 256, 0, stream>>>(
                xc, xz, dbc, delta, al, dd, hfin, sumd);
            scan_prefix_kernel<<<dim3(Bc * 80), 256, 0, stream>>>(hfin, sumd, al, Bc);
            scan_fix_kernel<<<dim3(5, NCHUNK, Bc), 256, 0, stream>>>(
                xz, dbc, delta, al, hfin);
            // outproj + elu: (Mc x1280)@(320x1280)^T -> u (bf16)
            gemm_mfma_kernel<3, 128, 64, 64, unsigned short>
                <<<dim3(5, (unsigned)(Mc / 128)), 256, 0, stream>>>(
                xz, wout + (long)i * DMV * DIV, nullptr, u, DMV, DIV, 2 * DIV, DMV);
        }

        // fused head on last token of each batch in chunk
        head_kernel<<<Bc, 512, 0, stream>>>(u, w1t, s1_b1, w2t, s1_b2,
                                            s1_w3, s1_b3, sm, (float*)d_out + b0);
    }
}

// Round 14
// 1174.043 us; speedup vs baseline: 1.1424x; 1.1100x over previous
//
#include <hip/hip_runtime.h>
#include <math.h>

// Problem constants
#define BSZ 8
#define LSZ 2048
#define DMV 320
#define DIV 1280
#define NST 16
#define DCV 8
#define DTR 20
#define NBLKV 4
#define MTOT (BSZ*LSZ)   // 16384
#define NCHUNK 64
#define CLEN 32          // NCHUNK*CLEN == LSZ
#define DBLD 56          // dbc leading dim (bf16), 16B-aligned rows

typedef __attribute__((ext_vector_type(8))) short short8;
typedef __attribute__((ext_vector_type(8))) unsigned short ushort8;
typedef __attribute__((ext_vector_type(4))) float floatx4;

__device__ inline unsigned short f2bf(float f) {
    union { float f; unsigned u; } v; v.f = f;
    unsigned r = v.u + 0x7FFFu + ((v.u >> 16) & 1u);
    return (unsigned short)(r >> 16);
}
__device__ inline float bf2f(unsigned short b) {
    union { unsigned u; float f; } v; v.u = ((unsigned)b) << 16;
    return v.f;
}

// async 16B global -> LDS (wave-uniform LDS base + lane*16) [m97 pattern]
__device__ __forceinline__ void gload_lds16(unsigned short* l, const unsigned short* g) {
    __builtin_amdgcn_global_load_lds(
        (const __attribute__((address_space(1))) unsigned int*)g,
        (__attribute__((address_space(3))) unsigned int*)l, 16, 0, 0);
}

// ---------------------------------------------------------------------------
// fp32 -> bf16 weight conversion (grid-stride, n % 4 == 0)
// ---------------------------------------------------------------------------
__global__ __launch_bounds__(256) void convert_kernel(
    const float* __restrict__ src, unsigned short* __restrict__ dst, long n4) {
    long i = (long)blockIdx.x * 256 + threadIdx.x;
    if (i >= n4) return;
    float4 v = *(const float4*)(src + i * 4);
    unsigned short o[4] = {f2bf(v.x), f2bf(v.y), f2bf(v.z), f2bf(v.w)};
    *(unsigned long long*)(dst + i * 4) = *(unsigned long long*)o;
}

// dtproj_w (NBLKV x 1280 x 20) -> bf16 padded (NBLKV x 1280 x 32), zero cols 20..31
__global__ __launch_bounds__(256) void convert_dtw_kernel(
    const float* __restrict__ src, unsigned short* __restrict__ dst) {
    int i = blockIdx.x * 256 + threadIdx.x;
    if (i >= NBLKV * DIV * 32) return;
    int l = i / (DIV * 32), rem = i % (DIV * 32);
    int d = rem >> 5, j = rem & 31;
    dst[i] = (j < DTR) ? f2bf(src[((long)l * DIV + d) * DTR + j]) : (unsigned short)0;
}

// xproj_w (NBLKV x 52 x 1280) -> bf16 padded (NBLKV x 64 x 1280), zero rows 52..63
__global__ __launch_bounds__(256) void convert_xp_kernel(
    const float* __restrict__ src, unsigned short* __restrict__ dst) {
    int i = blockIdx.x * 256 + threadIdx.x;
    if (i >= NBLKV * 64 * DIV) return;
    int l = i / (64 * DIV), rem = i % (64 * DIV);
    int n = rem / DIV, k = rem % DIV;
    dst[i] = (n < DTR + 2 * NST) ? f2bf(src[((long)l * (DTR + 2 * NST) + n) * DIV + k])
                                 : (unsigned short)0;
}

// head weight (N x K) fp32 -> pair-packed transposed bf16
__global__ __launch_bounds__(256) void convert_t2_kernel(
    const float* __restrict__ src, unsigned short* __restrict__ dst, int N, int K) {
    int i = blockIdx.x * 256 + threadIdx.x;
    if (i >= N * K) return;
    int n = i / K, k = i % K;
    dst[((k >> 1) * N + n) * 2 + (k & 1)] = f2bf(src[i]);
}

// ---------------------------------------------------------------------------
// start_max reduction (x[:,:,2] >= 0, so int-compare atomicMax is valid)
// ---------------------------------------------------------------------------
__global__ void init_sm_kernel(float* sm) {
    if (threadIdx.x == 0) ((int*)sm)[0] = 0;
}

__global__ void reduce_max_kernel(const float* __restrict__ x, float* sm) {
    int idx = blockIdx.x * blockDim.x + threadIdx.x;
    float v = 0.f;
    for (int i = idx; i < MTOT; i += gridDim.x * blockDim.x)
        v = fmaxf(v, x[i * 4 + 2]);
    #pragma unroll
    for (int off = 32; off > 0; off >>= 1)
        v = fmaxf(v, __shfl_xor(v, off, 64));
    if ((threadIdx.x & 63) == 0)
        atomicMax((int*)sm, __float_as_int(v));
}

// ---------------------------------------------------------------------------
// input normalize + fc (K=4) -> bf16 u
// ---------------------------------------------------------------------------
__global__ __launch_bounds__(256) void fc_kernel(
    const float* __restrict__ x, const float* __restrict__ fw,
    const float* __restrict__ fb, const float* __restrict__ sm,
    unsigned short* __restrict__ u) {
    int o = blockIdx.x * 64 + (threadIdx.x & 63);
    long m = (long)blockIdx.y * 4 + (threadIdx.x >> 6);
    float inv_sm = 1.0f / sm[0];
    float x0 = x[m * 4 + 0] * (1.0f / 255.0f);
    float x1 = x[m * 4 + 1] * (1.0f / 255.0f);
    float x2 = x[m * 4 + 2] * inv_sm;
    float x3 = x[m * 4 + 3];
    float acc = fb[o];
    acc = fmaf(x0, fw[o * 4 + 0], acc);
    acc = fmaf(x1, fw[o * 4 + 1], acc);
    acc = fmaf(x2, fw[o * 4 + 2], acc);
    acc = fmaf(x3, fw[o * 4 + 3], acc);
    u[m * DMV + o] = f2bf(acc);
}

// ---------------------------------------------------------------------------
// bf16 MFMA GEMM with async global->LDS staging + XOR chunk swizzle.
// XCD-aware block swizzle: each XCD (blocks lin%8 under round-robin dispatch)
// owns a partition of row-tiles and runs ALL column-tiles for them -> X row
// tiles are fetched into exactly one per-XCD L2 (kills cross-XCD re-fetch).
// Direct-store epilogue (R11; LDS-transpose variant regressed in R12).
// ---------------------------------------------------------------------------
template<int ACT, int BM, int BN, int KB, typename TOUT>
__global__ __launch_bounds__(256) void gemm_mfma_kernel(
    const unsigned short* __restrict__ X, const unsigned short* __restrict__ W,
    const float* __restrict__ bias, TOUT* __restrict__ Y,
    int N, int K, long ldx, long ldy)
{
    constexpr int WMT = (BM == 128 && BN == 128) ? 4 : 2;
    constexpr int WNT = (BM == 64 && BN == 64) ? 2 : 4;
    constexpr int CPR = KB / 8;                  // 16B chunks per row
    constexpr int CMSK = CPR - 1;
    constexpr int NCX = BM * CPR / 256;
    constexpr int NCW = BN * CPR / 256;
    __shared__ unsigned short Xs[BM * KB];
    __shared__ unsigned short Ws[BN * KB];

    int tid = threadIdx.x;
    int wave = tid >> 6, lane = tid & 63;
    int quad = lane >> 4, l15 = lane & 15;
    int wmbase, wnbase;
    if (BM == 128 && BN == 128)      { wmbase = (wave & 1) * 64; wnbase = (wave >> 1) * 64; }
    else if (BM == 128 && BN == 64)  { wmbase = wave * 32;       wnbase = 0; }
    else                             { wmbase = (wave & 1) * 32; wnbase = (wave >> 1) * 32; }

    // XCD-aware (bx, by) remap; identity if nby not a multiple of 8
    int nbx = gridDim.x;
    long by; int bx;
    if ((gridDim.y & 7) == 0) {
        long lin = (long)blockIdx.y * nbx + blockIdx.x;
        int xcd = (int)(lin & 7);
        long j = lin >> 3;
        bx = (int)(j % nbx);
        by = (j / nbx) * 8 + xcd;
    } else {
        bx = blockIdx.x;
        by = blockIdx.y;
    }
    long m0 = by * BM;
    int n0 = bx * BN;

    floatx4 acc[WMT][WNT];
    #pragma unroll
    for (int i = 0; i < WMT; i++)
        #pragma unroll
        for (int j = 0; j < WNT; j++)
            acc[i][j] = (floatx4){0.f, 0.f, 0.f, 0.f};

    const unsigned short* Xb = X + m0 * ldx;
    const unsigned short* Wb = W + (long)n0 * K;

    for (int k0 = 0; k0 < K; k0 += KB) {
        #pragma unroll
        for (int j = 0; j < NCX; j++) {
            int s = (wave * NCX + j) * 64 + lane;
            int r = s / CPR, c = s % CPR;
            int cg = c ^ (r & CMSK);
            gload_lds16(&Xs[(wave * NCX + j) * 512],
                        Xb + (long)r * ldx + k0 + cg * 8);
        }
        #pragma unroll
        for (int j = 0; j < NCW; j++) {
            int s = (wave * NCW + j) * 64 + lane;
            int r = s / CPR, c = s % CPR;
            int cg = c ^ (r & CMSK);
            gload_lds16(&Ws[(wave * NCW + j) * 512],
                        Wb + (long)r * K + k0 + cg * 8);
        }
        __syncthreads();
        #pragma unroll
        for (int kk = 0; kk < KB; kk += 32) {
            short8 af[WMT], bfr[WNT];
            #pragma unroll
            for (int i = 0; i < WMT; i++) {
                int R = wmbase + i * 16 + l15;
                int cp = (kk / 8 + quad) ^ (R & CMSK);
                af[i] = *(short8*)&Xs[R * KB + cp * 8];
            }
            #pragma unroll
            for (int j = 0; j < WNT; j++) {
                int R = wnbase + j * 16 + l15;
                int cp = (kk / 8 + quad) ^ (R & CMSK);
                bfr[j] = *(short8*)&Ws[R * KB + cp * 8];
            }
            #pragma unroll
            for (int i = 0; i < WMT; i++)
                #pragma unroll
                for (int j = 0; j < WNT; j++)
                    acc[i][j] = __builtin_amdgcn_mfma_f32_16x16x32_bf16(
                        af[i], bfr[j], acc[i][j], 0, 0, 0);
        }
        __syncthreads();
    }

    #pragma unroll
    for (int i = 0; i < WMT; i++) {
        long mb = m0 + wmbase + i * 16 + quad * 4;
        #pragma unroll
        for (int j = 0; j < WNT; j++) {
            int n = n0 + wnbase + j * 16 + l15;
            if (n >= N) continue;
            float bv = bias ? bias[n] : 0.f;
            #pragma unroll
            for (int r = 0; r < 4; r++) {
                float v = acc[i][j][r] + bv;
                if (ACT == 1) v = tanhf(v);
                else if (ACT == 3) v = (v > 0.f) ? v : expm1f(v);
                else if (ACT == 4) v = (v > 20.f) ? v : __logf(1.0f + __expf(v));
                if constexpr (sizeof(TOUT) == 2)
                    Y[(mb + r) * ldy + n] = f2bf(v);
                else
                    Y[(mb + r) * ldy + n] = v;
            }
        }
    }
}

// ---------------------------------------------------------------------------
// fused head, thread-per-output with pair-packed transposed bf16 weights.
// ---------------------------------------------------------------------------
__global__ __launch_bounds__(512) void head_kernel(
    const unsigned short* __restrict__ u,
    const unsigned short* __restrict__ w1t, const float* __restrict__ b1,
    const unsigned short* __restrict__ w2t, const float* __restrict__ b2,
    const float* __restrict__ w3, const float* __restrict__ b3,
    const float* __restrict__ sm, float* __restrict__ out)
{
    __shared__ float xs[DMV];
    __shared__ float h1s[512];
    __shared__ float red[8];
    int b = blockIdx.x;
    int tid = threadIdx.x;
    const unsigned short* xr = u + ((long)b * LSZ + (LSZ - 1)) * DMV;
    if (tid < DMV) xs[tid] = bf2f(xr[tid]);
    __syncthreads();

    float acc = 0.f;
    #pragma unroll 8
    for (int kk = 0; kk < DMV / 2; kk++) {
        unsigned wv = *(const unsigned*)&w1t[((long)kk * 512 + tid) * 2];
        acc = fmaf(xs[2 * kk],     bf2f((unsigned short)(wv & 0xffffu)), acc);
        acc = fmaf(xs[2 * kk + 1], bf2f((unsigned short)(wv >> 16)), acc);
    }
    h1s[tid] = fmaxf(acc + b1[tid], 0.f);
    __syncthreads();

    acc = 0.f;
    #pragma unroll 8
    for (int kk = 0; kk < 256; kk++) {
        unsigned wv = *(const unsigned*)&w2t[((long)kk * 512 + tid) * 2];
        acc = fmaf(h1s[2 * kk],     bf2f((unsigned short)(wv & 0xffffu)), acc);
        acc = fmaf(h1s[2 * kk + 1], bf2f((unsigned short)(wv >> 16)), acc);
    }
    float h2 = fmaxf(acc + b2[tid], 0.f);

    float part = h2 * w3[tid];
    #pragma unroll
    for (int off = 32; off > 0; off >>= 1) part += __shfl_xor(part, off, 64);
    if ((tid & 63) == 0) red[tid >> 6] = part;
    __syncthreads();
    if (tid == 0) {
        float s = b3[0];
        #pragma unroll
        for (int w = 0; w < 8; w++) s += red[w];
        float scale = sm[0] / 8.624618986159398f;   // 1 + ln(2048)
        out[b] = fmaxf(s * scale, 0.f);
    }
}

// ---------------------------------------------------------------------------
// depthwise causal conv (k=8) + bias + silu, sliding-window, bf16
// ---------------------------------------------------------------------------
#define TCONV 32
__global__ __launch_bounds__(256) void conv_kernel(
    const unsigned short* __restrict__ xz, const float* __restrict__ cw,
    const float* __restrict__ cb, unsigned short* __restrict__ xc)
{
    int d = blockIdx.x * 256 + threadIdx.x;
    int lb = blockIdx.z;
    int l0 = blockIdx.y * TCONV;
    long base = (long)lb * LSZ + l0;

    float w[8];
    #pragma unroll
    for (int k = 0; k < 8; k++) w[k] = cw[d * 8 + k];
    float bc = cb[d];

    float win[8];
    #pragma unroll
    for (int i = 0; i < 7; i++) {
        int l = l0 - 7 + i;
        win[i] = (l >= 0) ? bf2f(xz[(base - 7 + i) * 2560 + d]) : 0.f;
    }
    #pragma unroll
    for (int s = 0; s < TCONV; s++) {
        win[7] = bf2f(xz[(base + s) * 2560 + d]);
        float acc = bc;
        #pragma unroll
        for (int k = 0; k < 8; k++) acc = fmaf(win[k], w[k], acc);
        float sv = acc / (1.0f + __expf(-acc));
        xc[(base + s) * DIV + d] = f2bf(sv);
        #pragma unroll
        for (int k = 0; k < 7; k++) win[k] = win[k + 1];
    }
}

// power ladder: pw[n] = p^(n+1)
__device__ inline void pow_ladder(float p, float* pw) {
    pw[0] = p;
    pw[1] = pw[0] * pw[0];
    pw[2] = pw[1] * pw[0];
    pw[3] = pw[1] * pw[1];
    pw[4] = pw[3] * pw[0];
    pw[5] = pw[3] * pw[1];
    pw[6] = pw[3] * pw[2];
    pw[7] = pw[3] * pw[3];
    #pragma unroll
    for (int k = 8; k < 16; k++) pw[k] = pw[7] * pw[k - 8];
}

// ---------------------------------------------------------------------------
// Chunked scan phase 1: per-chunk local scan (h0=0), CLEN=32.
// ---------------------------------------------------------------------------
__global__ __launch_bounds__(256) void scan_local_kernel(
    const unsigned short* __restrict__ xc, unsigned short* xz,
    const unsigned short* __restrict__ dbc, const unsigned short* __restrict__ delta,
    const float* __restrict__ A_log, const float* __restrict__ Dp,
    unsigned short* __restrict__ hfin, float* __restrict__ sumd)
{
    __shared__ float S[CLEN * 32];
    int lb = blockIdx.z;
    int ch = blockIdx.y;
    int d = blockIdx.x * 256 + threadIdx.x;
    int tid = threadIdx.x;

    float a[NST], h[NST];
    #pragma unroll
    for (int n = 0; n < NST; n++) {
        a[n] = -__expf(A_log[d * NST + n]);
        h[n] = 0.f;
    }
    float a0 = a[0];
    bool geo = true;
    #pragma unroll
    for (int n = 1; n < NST; n++)
        geo = geo && (fabsf(a[n] - (float)(n + 1) * a0) <= 1e-4f * (float)(n + 1));
    float Dd = Dp[d];

    long tok0 = (long)lb * LSZ + ch * CLEN;
    for (int i = tid; i < CLEN * 32; i += 256) {
        int r = i >> 5, c = i & 31;
        S[i] = bf2f(dbc[(tok0 + r) * DBLD + 20 + c]);
    }
    __syncthreads();

    float sd = 0.f;
    if (__all(geo)) {
        for (int l = 0; l < CLEN; l++) {
            long m = tok0 + l;
            const float* row = &S[l * 32];
            float dl = bf2f(delta[m * DIV + d]);
            sd += dl;
            float xv = bf2f(xc[m * DIV + d]);
            float db = dl * xv;
            float pw[NST];
            pow_ladder(__expf(dl * a0), pw);
            float y = 0.f;
            #pragma unroll
            for (int n = 0; n < NST; n++) {
                h[n] = fmaf(pw[n], h[n], db * row[n]);
                y = fmaf(h[n], row[16 + n], y);
            }
            y = fmaf(xv, Dd, y);
            xz[m * 2560 + d] = f2bf(y);
        }
    } else {
        for (int l = 0; l < CLEN; l++) {
            long m = tok0 + l;
            const float* row = &S[l * 32];
            float dl = bf2f(delta[m * DIV + d]);
            sd += dl;
            float xv = bf2f(xc[m * DIV + d]);
            float db = dl * xv;
            float y = 0.f;
            #pragma unroll
            for (int n = 0; n < NST; n++) {
                float dA = __expf(dl * a[n]);
                h[n] = fmaf(dA, h[n], db * row[n]);
                y = fmaf(h[n], row[16 + n], y);
            }
            y = fmaf(xv, Dd, y);
            xz[m * 2560 + d] = f2bf(y);
        }
    }

    long cidx = ((long)lb * NCHUNK + ch) * DIV + d;
    #pragma unroll
    for (int n = 0; n < NST; n++) hfin[cidx * NST + n] = f2bf(h[n]);
    sumd[cidx] = sd;
}

// ---------------------------------------------------------------------------
// Phase 2: sequential prefix over chunks (bf16 hfin). One thread per (b,d,n).
// ---------------------------------------------------------------------------
__global__ __launch_bounds__(256) void scan_prefix_kernel(
    unsigned short* __restrict__ hfin, const float* __restrict__ sumd,
    const float* __restrict__ A_log, int Bc)
{
    long g = (long)blockIdx.x * 256 + threadIdx.x;
    int n = (int)(g & (NST - 1));
    long t = g >> 4;
    int d = (int)(t % DIV);
    int lb = (int)(t / DIV);
    if (lb >= Bc) return;

    float a = -__expf(A_log[d * NST + n]);
    float s = 0.f;
    for (int c = 0; c < NCHUNK; c++) {
        long cidx = ((long)lb * NCHUNK + c) * DIV + d;
        float hl = bf2f(hfin[cidx * NST + n]);
        float P = __expf(a * sumd[cidx]);
        hfin[cidx * NST + n] = f2bf(s);
        s = fmaf(P, s, hl);
    }
}

// ---------------------------------------------------------------------------
// Phase 3 (parallel over tokens; cheap serial cum recompute):
// y = y_local + C . (hin * exp(a*cum)), out = y * silu(z).
// ---------------------------------------------------------------------------
__global__ __launch_bounds__(256) void scan_fix_kernel(
    unsigned short* xz, const unsigned short* __restrict__ dbc,
    const unsigned short* __restrict__ delta,
    const float* __restrict__ A_log, const unsigned short* __restrict__ hfin)
{
    __shared__ float S[CLEN * 16];
    int lb = blockIdx.z;
    int ch = blockIdx.y;
    int d = blockIdx.x * 256 + threadIdx.x;
    int tid = threadIdx.x;

    float a[NST], hin[NST];
    #pragma unroll
    for (int n = 0; n < NST; n++) a[n] = -__expf(A_log[d * NST + n]);
    float a0 = a[0];
    bool geo = true;
    #pragma unroll
    for (int n = 1; n < NST; n++)
        geo = geo && (fabsf(a[n] - (float)(n + 1) * a0) <= 1e-4f * (float)(n + 1));

    long cidx = ((long)lb * NCHUNK + ch) * DIV + d;
    #pragma unroll
    for (int n = 0; n < NST; n++) hin[n] = bf2f(hfin[cidx * NST + n]);

    long tok0 = (long)lb * LSZ + ch * CLEN;
    for (int i = tid; i < CLEN * 16; i += 256) {
        int r = i >> 4, c = i & 15;
        S[i] = bf2f(dbc[(tok0 + r) * DBLD + 36 + c]);
    }
    __syncthreads();

    float cum = 0.f;
    if (__all(geo)) {
        for (int l = 0; l < CLEN; l++) {
            long m = tok0 + l;
            const float* row = &S[l * 16];
            cum += bf2f(delta[m * DIV + d]);
            float pw[NST];
            pow_ladder(__expf(cum * a0), pw);
            float fix = 0.f;
            #pragma unroll
            for (int n = 0; n < NST; n++)
                fix = fmaf(hin[n] * pw[n], row[n], fix);
            float y = bf2f(xz[m * 2560 + d]) + fix;
            float zv = bf2f(xz[m * 2560 + 1280 + d]);
            float sz = zv / (1.0f + __expf(-zv));
            xz[m * 2560 + d] = f2bf(y * sz);
        }
    } else {
        for (int l = 0; l < CLEN; l++) {
            long m = tok0 + l;
            const float* row = &S[l * 16];
            cum += bf2f(delta[m * DIV + d]);
            float fix = 0.f;
            #pragma unroll
            for (int n = 0; n < NST; n++)
                fix = fmaf(hin[n] * __expf(cum * a[n]), row[n], fix);
            float y = bf2f(xz[m * 2560 + d]) + fix;
            float zv = bf2f(xz[m * 2560 + 1280 + d]);
            float sz = zv / (1.0f + __expf(-zv));
            xz[m * 2560 + d] = f2bf(y * sz);
        }
    }
}

// ---------------------------------------------------------------------------
extern "C" void kernel_launch(void* const* d_in, const int* in_sizes, int n_in,
                              void* d_out, int out_size, void* d_ws, size_t ws_size,
                              hipStream_t stream) {
    const float* x        = (const float*)d_in[0];
    const float* fc_w     = (const float*)d_in[1];
    const float* fc_b     = (const float*)d_in[2];
    const float* lin_w    = (const float*)d_in[3];
    const float* lin_b    = (const float*)d_in[4];
    const float* inproj_w = (const float*)d_in[5];
    const float* conv_w   = (const float*)d_in[6];
    const float* conv_b   = (const float*)d_in[7];
    const float* xproj_w  = (const float*)d_in[8];
    const float* dtproj_w = (const float*)d_in[9];
    const float* dtproj_b = (const float*)d_in[10];
    const float* A_log    = (const float*)d_in[11];
    const float* Dp       = (const float*)d_in[12];
    const float* outproj_w= (const float*)d_in[13];
    const float* s1_w1    = (const float*)d_in[14];
    const float* s1_b1    = (const float*)d_in[15];
    const float* s1_w2    = (const float*)d_in[16];
    const float* s1_b2    = (const float*)d_in[17];
    const float* s1_w3    = (const float*)d_in[18];
    const float* s1_b3    = (const float*)d_in[19];

    const long NLIN = (long)NBLKV * DMV * DMV;
    const long NINP = (long)NBLKV * 2 * DIV * DMV;
    const long NXPP = (long)NBLKV * 64 * DIV;
    const long NOUT = (long)NBLKV * DMV * DIV;
    const long NDTW = (long)NBLKV * DIV * 32;
    const long NHW1 = (long)512 * DMV;
    const long NHW2 = (long)512 * 512;

    // ---- workspace sizing ----
    const long FIXED = 256 +
                       (NLIN + NINP + NXPP + NOUT + NDTW + NHW1 + NHW2) * 2 + 256;
    const long PER_BATCH = (long)LSZ * (DMV + DMV + 2 * DIV + DIV) * 2   // bf16 acts
                         + (long)LSZ * DBLD * 2                          // dbc bf16
                         + (long)LSZ * DIV * 2                           // delta bf16
                         + (long)NCHUNK * DIV * NST * 2                  // hfin bf16
                         + (long)NCHUNK * DIV * 4;                       // sumd
    int Bc = 8;
    while (Bc > 1 && (size_t)(FIXED + (long)Bc * PER_BATCH) > ws_size)
        Bc >>= 1;
    int nchunk_b = BSZ / Bc;
    long Mc = (long)Bc * LSZ;

    char* p = (char*)d_ws;
    float* sm = (float*)p;           p += 256;
    unsigned short* wlin = (unsigned short*)p; p += NLIN * 2;
    unsigned short* winp = (unsigned short*)p; p += NINP * 2;
    unsigned short* wxp  = (unsigned short*)p; p += NXPP * 2;
    unsigned short* wout = (unsigned short*)p; p += NOUT * 2;
    unsigned short* wdt  = (unsigned short*)p; p += NDTW * 2;
    unsigned short* w1t  = (unsigned short*)p; p += NHW1 * 2;
    unsigned short* w2t  = (unsigned short*)p; p += NHW2 * 2;
    unsigned short* u  = (unsigned short*)p;   p += Mc * DMV * 2;
    unsigned short* t  = (unsigned short*)p;   p += Mc * DMV * 2;
    unsigned short* xz = (unsigned short*)p;   p += Mc * 2560 * 2;
    unsigned short* xc = (unsigned short*)p;   p += Mc * DIV * 2;
    unsigned short* dbc = (unsigned short*)p;  p += Mc * DBLD * 2;
    unsigned short* delta = (unsigned short*)p; p += Mc * DIV * 2;
    unsigned short* hfin = (unsigned short*)p; p += (long)Bc * NCHUNK * DIV * NST * 2;
    float* sumd = (float*)p;

    // one-time (per launch) weight conversion
    convert_kernel<<<(unsigned)((NLIN / 4 + 255) / 256), 256, 0, stream>>>(lin_w, wlin, NLIN / 4);
    convert_kernel<<<(unsigned)((NINP / 4 + 255) / 256), 256, 0, stream>>>(inproj_w, winp, NINP / 4);
    convert_kernel<<<(unsigned)((NOUT / 4 + 255) / 256), 256, 0, stream>>>(outproj_w, wout, NOUT / 4);
    convert_xp_kernel<<<(unsigned)((NXPP + 255) / 256), 256, 0, stream>>>(xproj_w, wxp);
    convert_dtw_kernel<<<(unsigned)((NDTW + 255) / 256), 256, 0, stream>>>(dtproj_w, wdt);
    convert_t2_kernel<<<(unsigned)((NHW1 + 255) / 256), 256, 0, stream>>>(s1_w1, w1t, 512, DMV);
    convert_t2_kernel<<<(unsigned)((NHW2 + 255) / 256), 256, 0, stream>>>(s1_w2, w2t, 512, 512);

    init_sm_kernel<<<1, 64, 0, stream>>>(sm);
    reduce_max_kernel<<<32, 256, 0, stream>>>(x, sm);

    for (int c = 0; c < nchunk_b; c++) {
        int b0 = c * Bc;
        fc_kernel<<<dim3(5, (unsigned)(Mc / 4)), 256, 0, stream>>>(
            x + (long)b0 * LSZ * 4, fc_w, fc_b, sm, u);

        for (int i = 0; i < NBLKV; i++) {
            const float* lb  = lin_b    + (long)i * DMV;
            const float* cw  = conv_w   + (long)i * DIV * DCV;
            const float* cb  = conv_b   + (long)i * DIV;
            const float* dpb = dtproj_b + (long)i * DIV;
            const float* al  = A_log    + (long)i * DIV * NST;
            const float* dd  = Dp       + (long)i * DIV;

            // lin + tanh: (Mc x320)@(320x320)^T -> t (bf16)
            gemm_mfma_kernel<1, 128, 64, 64, unsigned short>
                <<<dim3(5, (unsigned)(Mc / 128)), 256, 0, stream>>>(
                u, wlin + (long)i * DMV * DMV, lb, t, DMV, DMV, DMV, DMV);
            // inproj: (Mc x320)@(2560x320)^T -> xz (bf16)
            gemm_mfma_kernel<0, 128, 128, 64, unsigned short>
                <<<dim3(20, (unsigned)(Mc / 128)), 256, 0, stream>>>(
                t, winp + (long)i * 2 * DIV * DMV, nullptr, xz, 2 * DIV, DMV, DMV, 2 * DIV);
            // conv + silu (sliding window, bf16)
            conv_kernel<<<dim3(5, LSZ / TCONV, Bc), 256, 0, stream>>>(xz, cw, cb, xc);
            // xproj: (Mc x1280)@(64x1280)^T (padded W) -> dbc (bf16, ld 56)
            gemm_mfma_kernel<0, 64, 64, 64, unsigned short>
                <<<dim3(1, (unsigned)(Mc / 64)), 256, 0, stream>>>(
                xc, wxp + (long)i * 64 * DIV, nullptr, dbc,
                DTR + 2 * NST, DIV, DIV, DBLD);
            // delta = softplus(dbc[:, :20] @ dtw^T + b): K padded to 32, bf16 out
            gemm_mfma_kernel<4, 128, 128, 32, unsigned short>
                <<<dim3(10, (unsigned)(Mc / 128)), 256, 0, stream>>>(
                dbc, wdt + (long)i * DIV * 32, dpb, delta, DIV, 32, DBLD, DIV);
            // chunked scan (CLEN=32, NCHUNK=64)
            scan_local_kernel<<<dim3(5, NCHUNK, Bc), 256, 0, stream>>>(
                xc, xz, dbc, delta, al, dd, hfin, sumd);
            scan_prefix_kernel<<<dim3(Bc * 80), 256, 0, stream>>>(hfin, sumd, al, Bc);
            scan_fix_kernel<<<dim3(5, NCHUNK, Bc), 256, 0, stream>>>(
                xz, dbc, delta, al, hfin);
            // outproj + elu: (Mc x1280)@(320x1280)^T -> u (bf16)
            gemm_mfma_kernel<3, 128, 64, 64, unsigned short>
                <<<dim3(5, (unsigned)(Mc / 128)), 256, 0, stream>>>(
                xz, wout + (long)i * DMV * DIV, nullptr, u, DMV, DIV, 2 * DIV, DMV);
        }

        // fused head on last token of each batch in chunk
        head_kernel<<<Bc, 512, 0, stream>>>(u, w1t, s1_b1, w2t, s1_b2,
                                            s1_w3, s1_b3, sm, (float*)d_out + b0);
    }
}

// Round 15
// 1113.172 us; speedup vs baseline: 1.2048x; 1.0547x over previous
//
#include <hip/hip_runtime.h>
#include <math.h>

// Problem constants
#define BSZ 8
#define LSZ 2048
#define DMV 320
#define DIV 1280
#define NST 16
#define DCV 8
#define DTR 20
#define NBLKV 4
#define MTOT (BSZ*LSZ)   // 16384
#define NCHUNK 64
#define CLEN 32          // NCHUNK*CLEN == LSZ
#define DBLD 56          // dbc leading dim (bf16), 16B-aligned rows

typedef __attribute__((ext_vector_type(8))) short short8;
typedef __attribute__((ext_vector_type(8))) unsigned short ushort8;
typedef __attribute__((ext_vector_type(4))) float floatx4;

__device__ inline unsigned short f2bf(float f) {
    union { float f; unsigned u; } v; v.f = f;
    unsigned r = v.u + 0x7FFFu + ((v.u >> 16) & 1u);
    return (unsigned short)(r >> 16);
}
__device__ inline float bf2f(unsigned short b) {
    union { unsigned u; float f; } v; v.u = ((unsigned)b) << 16;
    return v.f;
}

// async 16B global -> LDS (wave-uniform LDS base + lane*16) [m97 pattern]
__device__ __forceinline__ void gload_lds16(unsigned short* l, const unsigned short* g) {
    __builtin_amdgcn_global_load_lds(
        (const __attribute__((address_space(1))) unsigned int*)g,
        (__attribute__((address_space(3))) unsigned int*)l, 16, 0, 0);
}

// ---------------------------------------------------------------------------
// fp32 -> bf16 weight conversion (grid-stride, n % 4 == 0)
// ---------------------------------------------------------------------------
__global__ __launch_bounds__(256) void convert_kernel(
    const float* __restrict__ src, unsigned short* __restrict__ dst, long n4) {
    long i = (long)blockIdx.x * 256 + threadIdx.x;
    if (i >= n4) return;
    float4 v = *(const float4*)(src + i * 4);
    unsigned short o[4] = {f2bf(v.x), f2bf(v.y), f2bf(v.z), f2bf(v.w)};
    *(unsigned long long*)(dst + i * 4) = *(unsigned long long*)o;
}

// dtproj_w (NBLKV x 1280 x 20) -> bf16 padded (NBLKV x 1280 x 32)
__global__ __launch_bounds__(256) void convert_dtw_kernel(
    const float* __restrict__ src, unsigned short* __restrict__ dst) {
    int i = blockIdx.x * 256 + threadIdx.x;
    if (i >= NBLKV * DIV * 32) return;
    int l = i / (DIV * 32), rem = i % (DIV * 32);
    int d = rem >> 5, j = rem & 31;
    dst[i] = (j < DTR) ? f2bf(src[((long)l * DIV + d) * DTR + j]) : (unsigned short)0;
}

// xproj_w (NBLKV x 52 x 1280) -> bf16 padded (NBLKV x 64 x 1280)
__global__ __launch_bounds__(256) void convert_xp_kernel(
    const float* __restrict__ src, unsigned short* __restrict__ dst) {
    int i = blockIdx.x * 256 + threadIdx.x;
    if (i >= NBLKV * 64 * DIV) return;
    int l = i / (64 * DIV), rem = i % (64 * DIV);
    int n = rem / DIV, k = rem % DIV;
    dst[i] = (n < DTR + 2 * NST) ? f2bf(src[((long)l * (DTR + 2 * NST) + n) * DIV + k])
                                 : (unsigned short)0;
}

// head weight (N x K) fp32 -> pair-packed transposed bf16
__global__ __launch_bounds__(256) void convert_t2_kernel(
    const float* __restrict__ src, unsigned short* __restrict__ dst, int N, int K) {
    int i = blockIdx.x * 256 + threadIdx.x;
    if (i >= N * K) return;
    int n = i / K, k = i % K;
    dst[((k >> 1) * N + n) * 2 + (k & 1)] = f2bf(src[i]);
}

// ---------------------------------------------------------------------------
// start_max reduction (x[:,:,2] >= 0, so int-compare atomicMax is valid)
// ---------------------------------------------------------------------------
__global__ void init_sm_kernel(float* sm) {
    if (threadIdx.x == 0) ((int*)sm)[0] = 0;
}

__global__ void reduce_max_kernel(const float* __restrict__ x, float* sm) {
    int idx = blockIdx.x * blockDim.x + threadIdx.x;
    float v = 0.f;
    for (int i = idx; i < MTOT; i += gridDim.x * blockDim.x)
        v = fmaxf(v, x[i * 4 + 2]);
    #pragma unroll
    for (int off = 32; off > 0; off >>= 1)
        v = fmaxf(v, __shfl_xor(v, off, 64));
    if ((threadIdx.x & 63) == 0)
        atomicMax((int*)sm, __float_as_int(v));
}

// ---------------------------------------------------------------------------
// input normalize + fc (K=4) -> bf16 u
// ---------------------------------------------------------------------------
__global__ __launch_bounds__(256) void fc_kernel(
    const float* __restrict__ x, const float* __restrict__ fw,
    const float* __restrict__ fb, const float* __restrict__ sm,
    unsigned short* __restrict__ u) {
    int o = blockIdx.x * 64 + (threadIdx.x & 63);
    long m = (long)blockIdx.y * 4 + (threadIdx.x >> 6);
    float inv_sm = 1.0f / sm[0];
    float x0 = x[m * 4 + 0] * (1.0f / 255.0f);
    float x1 = x[m * 4 + 1] * (1.0f / 255.0f);
    float x2 = x[m * 4 + 2] * inv_sm;
    float x3 = x[m * 4 + 3];
    float acc = fb[o];
    acc = fmaf(x0, fw[o * 4 + 0], acc);
    acc = fmaf(x1, fw[o * 4 + 1], acc);
    acc = fmaf(x2, fw[o * 4 + 2], acc);
    acc = fmaf(x3, fw[o * 4 + 3], acc);
    u[m * DMV + o] = f2bf(acc);
}

// ---------------------------------------------------------------------------
// bf16 MFMA GEMM with async global->LDS staging + XOR chunk swizzle +
// XCD-aware block swizzle. T threads (256 or 512). Direct-store epilogue.
// ---------------------------------------------------------------------------
template<int ACT, int BM, int BN, int KB, int T, typename TOUT>
__global__ __launch_bounds__(T) void gemm_mfma_kernel(
    const unsigned short* __restrict__ X, const unsigned short* __restrict__ W,
    const float* __restrict__ bias, TOUT* __restrict__ Y,
    int N, int K, long ldx, long ldy)
{
    constexpr int WMT = (BM == 256) ? 4
                      : (BM == 128 && BN == 128) ? 4
                      : (BM == 128 && BN == 64) ? 2
                      : (BM == 64) ? 2 : 1;
    constexpr int WNT = (BM == 256) ? 4
                      : (BM == 128 && BN == 128) ? 4
                      : (BM == 128 && BN == 64) ? 4
                      : (BM == 64) ? 2 : 2;
    constexpr int CPR = KB / 8;                  // 16B chunks per row
    constexpr int CMSK = CPR - 1;
    constexpr int NCX = BM * CPR / T;
    constexpr int NCW = BN * CPR / T;
    __shared__ unsigned short Xs[BM * KB];
    __shared__ unsigned short Ws[BN * KB];

    int tid = threadIdx.x;
    int wave = tid >> 6, lane = tid & 63;
    int quad = lane >> 4, l15 = lane & 15;
    int wmbase, wnbase;
    if (BM == 256)                        { wmbase = (wave & 3) * 64; wnbase = (wave >> 2) * 64; }
    else if (BM == 128 && BN == 128)      { wmbase = (wave & 1) * 64; wnbase = (wave >> 1) * 64; }
    else if (BM == 128 && BN == 64)       { wmbase = wave * 32;       wnbase = 0; }
    else if (BM == 64)                    { wmbase = (wave & 1) * 32; wnbase = (wave >> 1) * 32; }
    else                                  { wmbase = (wave & 1) * 16; wnbase = (wave >> 1) * 32; }

    // XCD-aware (bx, by) remap; identity if nby not a multiple of 8
    int nbx = gridDim.x;
    long by; int bx;
    if ((gridDim.y & 7) == 0) {
        long lin = (long)blockIdx.y * nbx + blockIdx.x;
        int xcd = (int)(lin & 7);
        long j = lin >> 3;
        bx = (int)(j % nbx);
        by = (j / nbx) * 8 + xcd;
    } else {
        bx = blockIdx.x;
        by = blockIdx.y;
    }
    long m0 = by * BM;
    int n0 = bx * BN;

    floatx4 acc[WMT][WNT];
    #pragma unroll
    for (int i = 0; i < WMT; i++)
        #pragma unroll
        for (int j = 0; j < WNT; j++)
            acc[i][j] = (floatx4){0.f, 0.f, 0.f, 0.f};

    const unsigned short* Xb = X + m0 * ldx;
    const unsigned short* Wb = W + (long)n0 * K;

    for (int k0 = 0; k0 < K; k0 += KB) {
        #pragma unroll
        for (int j = 0; j < NCX; j++) {
            int s = (wave * NCX + j) * 64 + lane;
            int r = s / CPR, c = s % CPR;
            int cg = c ^ (r & CMSK);
            gload_lds16(&Xs[(wave * NCX + j) * 512],
                        Xb + (long)r * ldx + k0 + cg * 8);
        }
        #pragma unroll
        for (int j = 0; j < NCW; j++) {
            int s = (wave * NCW + j) * 64 + lane;
            int r = s / CPR, c = s % CPR;
            int cg = c ^ (r & CMSK);
            gload_lds16(&Ws[(wave * NCW + j) * 512],
                        Wb + (long)r * K + k0 + cg * 8);
        }
        __syncthreads();
        #pragma unroll
        for (int kk = 0; kk < KB; kk += 32) {
            short8 af[WMT], bfr[WNT];
            #pragma unroll
            for (int i = 0; i < WMT; i++) {
                int R = wmbase + i * 16 + l15;
                int cp = (kk / 8 + quad) ^ (R & CMSK);
                af[i] = *(short8*)&Xs[R * KB + cp * 8];
            }
            #pragma unroll
            for (int j = 0; j < WNT; j++) {
                int R = wnbase + j * 16 + l15;
                int cp = (kk / 8 + quad) ^ (R & CMSK);
                bfr[j] = *(short8*)&Ws[R * KB + cp * 8];
            }
            #pragma unroll
            for (int i = 0; i < WMT; i++)
                #pragma unroll
                for (int j = 0; j < WNT; j++)
                    acc[i][j] = __builtin_amdgcn_mfma_f32_16x16x32_bf16(
                        af[i], bfr[j], acc[i][j], 0, 0, 0);
        }
        __syncthreads();
    }

    #pragma unroll
    for (int i = 0; i < WMT; i++) {
        long mb = m0 + wmbase + i * 16 + quad * 4;
        #pragma unroll
        for (int j = 0; j < WNT; j++) {
            int n = n0 + wnbase + j * 16 + l15;
            if (n >= N) continue;
            float bv = bias ? bias[n] : 0.f;
            #pragma unroll
            for (int r = 0; r < 4; r++) {
                float v = acc[i][j][r] + bv;
                if (ACT == 1) v = tanhf(v);
                else if (ACT == 3) v = (v > 0.f) ? v : expm1f(v);
                else if (ACT == 4) v = (v > 20.f) ? v : __logf(1.0f + __expf(v));
                if constexpr (sizeof(TOUT) == 2)
                    Y[(mb + r) * ldy + n] = f2bf(v);
                else
                    Y[(mb + r) * ldy + n] = v;
            }
        }
    }
}

// ---------------------------------------------------------------------------
// fused head, thread-per-output with pair-packed transposed bf16 weights.
// ---------------------------------------------------------------------------
__global__ __launch_bounds__(512) void head_kernel(
    const unsigned short* __restrict__ u,
    const unsigned short* __restrict__ w1t, const float* __restrict__ b1,
    const unsigned short* __restrict__ w2t, const float* __restrict__ b2,
    const float* __restrict__ w3, const float* __restrict__ b3,
    const float* __restrict__ sm, float* __restrict__ out)
{
    __shared__ float xs[DMV];
    __shared__ float h1s[512];
    __shared__ float red[8];
    int b = blockIdx.x;
    int tid = threadIdx.x;
    const unsigned short* xr = u + ((long)b * LSZ + (LSZ - 1)) * DMV;
    if (tid < DMV) xs[tid] = bf2f(xr[tid]);
    __syncthreads();

    float acc = 0.f;
    #pragma unroll 8
    for (int kk = 0; kk < DMV / 2; kk++) {
        unsigned wv = *(const unsigned*)&w1t[((long)kk * 512 + tid) * 2];
        acc = fmaf(xs[2 * kk],     bf2f((unsigned short)(wv & 0xffffu)), acc);
        acc = fmaf(xs[2 * kk + 1], bf2f((unsigned short)(wv >> 16)), acc);
    }
    h1s[tid] = fmaxf(acc + b1[tid], 0.f);
    __syncthreads();

    acc = 0.f;
    #pragma unroll 8
    for (int kk = 0; kk < 256; kk++) {
        unsigned wv = *(const unsigned*)&w2t[((long)kk * 512 + tid) * 2];
        acc = fmaf(h1s[2 * kk],     bf2f((unsigned short)(wv & 0xffffu)), acc);
        acc = fmaf(h1s[2 * kk + 1], bf2f((unsigned short)(wv >> 16)), acc);
    }
    float h2 = fmaxf(acc + b2[tid], 0.f);

    float part = h2 * w3[tid];
    #pragma unroll
    for (int off = 32; off > 0; off >>= 1) part += __shfl_xor(part, off, 64);
    if ((tid & 63) == 0) red[tid >> 6] = part;
    __syncthreads();
    if (tid == 0) {
        float s = b3[0];
        #pragma unroll
        for (int w = 0; w < 8; w++) s += red[w];
        float scale = sm[0] / 8.624618986159398f;   // 1 + ln(2048)
        out[b] = fmaxf(s * scale, 0.f);
    }
}

// ---------------------------------------------------------------------------
// depthwise causal conv (k=8) + bias + silu, sliding-window, bf16.
// 2 channels per thread (uint loads/stores). 128 threads cover 256 channels.
// grid (DIV/256, LSZ/TCONV, Bc)
// ---------------------------------------------------------------------------
#define TCONV 32
__global__ __launch_bounds__(128) void conv_kernel(
    const unsigned short* __restrict__ xz, const float* __restrict__ cw,
    const float* __restrict__ cb, unsigned short* __restrict__ xc)
{
    int d0 = blockIdx.x * 256 + threadIdx.x * 2;
    int lb = blockIdx.z;
    int l0 = blockIdx.y * TCONV;
    long base = (long)lb * LSZ + l0;

    float w0[8], w1[8];
    #pragma unroll
    for (int k = 0; k < 8; k++) { w0[k] = cw[d0 * 8 + k]; w1[k] = cw[(d0 + 1) * 8 + k]; }
    float bc0 = cb[d0], bc1 = cb[d0 + 1];

    float a0[8], a1[8];
    #pragma unroll
    for (int i = 0; i < 7; i++) {
        int l = l0 - 7 + i;
        if (l >= 0) {
            unsigned v = *(const unsigned*)&xz[(base - 7 + i) * 2560 + d0];
            a0[i] = bf2f((unsigned short)(v & 0xffffu));
            a1[i] = bf2f((unsigned short)(v >> 16));
        } else { a0[i] = 0.f; a1[i] = 0.f; }
    }
    #pragma unroll
    for (int s = 0; s < TCONV; s++) {
        unsigned v = *(const unsigned*)&xz[(base + s) * 2560 + d0];
        a0[7] = bf2f((unsigned short)(v & 0xffffu));
        a1[7] = bf2f((unsigned short)(v >> 16));
        float c0 = bc0, c1 = bc1;
        #pragma unroll
        for (int k = 0; k < 8; k++) { c0 = fmaf(a0[k], w0[k], c0); c1 = fmaf(a1[k], w1[k], c1); }
        float s0 = c0 / (1.0f + __expf(-c0));
        float s1 = c1 / (1.0f + __expf(-c1));
        unsigned o = (unsigned)f2bf(s0) | ((unsigned)f2bf(s1) << 16);
        *(unsigned*)&xc[(base + s) * DIV + d0] = o;
        #pragma unroll
        for (int k = 0; k < 7; k++) { a0[k] = a0[k + 1]; a1[k] = a1[k + 1]; }
    }
}

// power ladder: pw[n] = p^(n+1)
__device__ inline void pow_ladder(float p, float* pw) {
    pw[0] = p;
    pw[1] = pw[0] * pw[0];
    pw[2] = pw[1] * pw[0];
    pw[3] = pw[1] * pw[1];
    pw[4] = pw[3] * pw[0];
    pw[5] = pw[3] * pw[1];
    pw[6] = pw[3] * pw[2];
    pw[7] = pw[3] * pw[3];
    #pragma unroll
    for (int k = 8; k < 16; k++) pw[k] = pw[7] * pw[k - 8];
}

// ---------------------------------------------------------------------------
// Chunked scan phase 1: per-chunk local scan (h0=0), CLEN=32.
// ---------------------------------------------------------------------------
__global__ __launch_bounds__(256) void scan_local_kernel(
    const unsigned short* __restrict__ xc, unsigned short* xz,
    const unsigned short* __restrict__ dbc, const unsigned short* __restrict__ delta,
    const float* __restrict__ A_log, const float* __restrict__ Dp,
    unsigned short* __restrict__ hfin, float* __restrict__ sumd)
{
    __shared__ float S[CLEN * 32];
    int lb = blockIdx.z;
    int ch = blockIdx.y;
    int d = blockIdx.x * 256 + threadIdx.x;
    int tid = threadIdx.x;

    float a[NST], h[NST];
    #pragma unroll
    for (int n = 0; n < NST; n++) {
        a[n] = -__expf(A_log[d * NST + n]);
        h[n] = 0.f;
    }
    float a0 = a[0];
    bool geo = true;
    #pragma unroll
    for (int n = 1; n < NST; n++)
        geo = geo && (fabsf(a[n] - (float)(n + 1) * a0) <= 1e-4f * (float)(n + 1));
    float Dd = Dp[d];

    long tok0 = (long)lb * LSZ + ch * CLEN;
    for (int i = tid; i < CLEN * 32; i += 256) {
        int r = i >> 5, c = i & 31;
        S[i] = bf2f(dbc[(tok0 + r) * DBLD + 20 + c]);
    }
    __syncthreads();

    float sd = 0.f;
    if (__all(geo)) {
        for (int l = 0; l < CLEN; l++) {
            long m = tok0 + l;
            const float* row = &S[l * 32];
            float dl = bf2f(delta[m * DIV + d]);
            sd += dl;
            float xv = bf2f(xc[m * DIV + d]);
            float db = dl * xv;
            float pw[NST];
            pow_ladder(__expf(dl * a0), pw);
            float y = 0.f;
            #pragma unroll
            for (int n = 0; n < NST; n++) {
                h[n] = fmaf(pw[n], h[n], db * row[n]);
                y = fmaf(h[n], row[16 + n], y);
            }
            y = fmaf(xv, Dd, y);
            xz[m * 2560 + d] = f2bf(y);
        }
    } else {
        for (int l = 0; l < CLEN; l++) {
            long m = tok0 + l;
            const float* row = &S[l * 32];
            float dl = bf2f(delta[m * DIV + d]);
            sd += dl;
            float xv = bf2f(xc[m * DIV + d]);
            float db = dl * xv;
            float y = 0.f;
            #pragma unroll
            for (int n = 0; n < NST; n++) {
                float dA = __expf(dl * a[n]);
                h[n] = fmaf(dA, h[n], db * row[n]);
                y = fmaf(h[n], row[16 + n], y);
            }
            y = fmaf(xv, Dd, y);
            xz[m * 2560 + d] = f2bf(y);
        }
    }

    long cidx = ((long)lb * NCHUNK + ch) * DIV + d;
    #pragma unroll
    for (int n = 0; n < NST; n++) hfin[cidx * NST + n] = f2bf(h[n]);
    sumd[cidx] = sd;
}

// ---------------------------------------------------------------------------
// Phase 2: sequential prefix over chunks (bf16 hfin). One thread per (b,d,n).
// ---------------------------------------------------------------------------
__global__ __launch_bounds__(256) void scan_prefix_kernel(
    unsigned short* __restrict__ hfin, const float* __restrict__ sumd,
    const float* __restrict__ A_log, int Bc)
{
    long g = (long)blockIdx.x * 256 + threadIdx.x;
    int n = (int)(g & (NST - 1));
    long t = g >> 4;
    int d = (int)(t % DIV);
    int lb = (int)(t / DIV);
    if (lb >= Bc) return;

    float a = -__expf(A_log[d * NST + n]);
    float s = 0.f;
    for (int c = 0; c < NCHUNK; c++) {
        long cidx = ((long)lb * NCHUNK + c) * DIV + d;
        float hl = bf2f(hfin[cidx * NST + n]);
        float P = __expf(a * sumd[cidx]);
        hfin[cidx * NST + n] = f2bf(s);
        s = fmaf(P, s, hl);
    }
}

// ---------------------------------------------------------------------------
// Phase 3 (parallel over tokens; cheap serial cum recompute):
// y = y_local + C . (hin * exp(a*cum)), out = y * silu(z).
// ---------------------------------------------------------------------------
__global__ __launch_bounds__(256) void scan_fix_kernel(
    unsigned short* xz, const unsigned short* __restrict__ dbc,
    const unsigned short* __restrict__ delta,
    const float* __restrict__ A_log, const unsigned short* __restrict__ hfin)
{
    __shared__ float S[CLEN * 16];
    int lb = blockIdx.z;
    int ch = blockIdx.y;
    int d = blockIdx.x * 256 + threadIdx.x;
    int tid = threadIdx.x;

    float a[NST], hin[NST];
    #pragma unroll
    for (int n = 0; n < NST; n++) a[n] = -__expf(A_log[d * NST + n]);
    float a0 = a[0];
    bool geo = true;
    #pragma unroll
    for (int n = 1; n < NST; n++)
        geo = geo && (fabsf(a[n] - (float)(n + 1) * a0) <= 1e-4f * (float)(n + 1));

    long cidx = ((long)lb * NCHUNK + ch) * DIV + d;
    #pragma unroll
    for (int n = 0; n < NST; n++) hin[n] = bf2f(hfin[cidx * NST + n]);

    long tok0 = (long)lb * LSZ + ch * CLEN;
    for (int i = tid; i < CLEN * 16; i += 256) {
        int r = i >> 4, c = i & 15;
        S[i] = bf2f(dbc[(tok0 + r) * DBLD + 36 + c]);
    }
    __syncthreads();

    float cum = 0.f;
    if (__all(geo)) {
        for (int l = 0; l < CLEN; l++) {
            long m = tok0 + l;
            const float* row = &S[l * 16];
            cum += bf2f(delta[m * DIV + d]);
            float pw[NST];
            pow_ladder(__expf(cum * a0), pw);
            float fix = 0.f;
            #pragma unroll
            for (int n = 0; n < NST; n++)
                fix = fmaf(hin[n] * pw[n], row[n], fix);
            float y = bf2f(xz[m * 2560 + d]) + fix;
            float zv = bf2f(xz[m * 2560 + 1280 + d]);
            float sz = zv / (1.0f + __expf(-zv));
            xz[m * 2560 + d] = f2bf(y * sz);
        }
    } else {
        for (int l = 0; l < CLEN; l++) {
            long m = tok0 + l;
            const float* row = &S[l * 16];
            cum += bf2f(delta[m * DIV + d]);
            float fix = 0.f;
            #pragma unroll
            for (int n = 0; n < NST; n++)
                fix = fmaf(hin[n] * __expf(cum * a[n]), row[n], fix);
            float y = bf2f(xz[m * 2560 + d]) + fix;
            float zv = bf2f(xz[m * 2560 + 1280 + d]);
            float sz = zv / (1.0f + __expf(-zv));
            xz[m * 2560 + d] = f2bf(y * sz);
        }
    }
}

// ---------------------------------------------------------------------------
extern "C" void kernel_launch(void* const* d_in, const int* in_sizes, int n_in,
                              void* d_out, int out_size, void* d_ws, size_t ws_size,
                              hipStream_t stream) {
    const float* x        = (const float*)d_in[0];
    const float* fc_w     = (const float*)d_in[1];
    const float* fc_b     = (const float*)d_in[2];
    const float* lin_w    = (const float*)d_in[3];
    const float* lin_b    = (const float*)d_in[4];
    const float* inproj_w = (const float*)d_in[5];
    const float* conv_w   = (const float*)d_in[6];
    const float* conv_b   = (const float*)d_in[7];
    const float* xproj_w  = (const float*)d_in[8];
    const float* dtproj_w = (const float*)d_in[9];
    const float* dtproj_b = (const float*)d_in[10];
    const float* A_log    = (const float*)d_in[11];
    const float* Dp       = (const float*)d_in[12];
    const float* outproj_w= (const float*)d_in[13];
    const float* s1_w1    = (const float*)d_in[14];
    const float* s1_b1    = (const float*)d_in[15];
    const float* s1_w2    = (const float*)d_in[16];
    const float* s1_b2    = (const float*)d_in[17];
    const float* s1_w3    = (const float*)d_in[18];
    const float* s1_b3    = (const float*)d_in[19];

    const long NLIN = (long)NBLKV * DMV * DMV;
    const long NINP = (long)NBLKV * 2 * DIV * DMV;
    const long NXPP = (long)NBLKV * 64 * DIV;
    const long NOUT = (long)NBLKV * DMV * DIV;
    const long NDTW = (long)NBLKV * DIV * 32;
    const long NHW1 = (long)512 * DMV;
    const long NHW2 = (long)512 * 512;

    // ---- workspace sizing ----
    const long FIXED = 256 +
                       (NLIN + NINP + NXPP + NOUT + NDTW + NHW1 + NHW2) * 2 + 256;
    const long PER_BATCH = (long)LSZ * (DMV + DMV + 2 * DIV + DIV) * 2   // bf16 acts
                         + (long)LSZ * DBLD * 2                          // dbc bf16
                         + (long)LSZ * DIV * 2                           // delta bf16
                         + (long)NCHUNK * DIV * NST * 2                  // hfin bf16
                         + (long)NCHUNK * DIV * 4;                       // sumd
    int Bc = 8;
    while (Bc > 1 && (size_t)(FIXED + (long)Bc * PER_BATCH) > ws_size)
        Bc >>= 1;
    int nchunk_b = BSZ / Bc;
    long Mc = (long)Bc * LSZ;

    char* p = (char*)d_ws;
    float* sm = (float*)p;           p += 256;
    unsigned short* wlin = (unsigned short*)p; p += NLIN * 2;
    unsigned short* winp = (unsigned short*)p; p += NINP * 2;
    unsigned short* wxp  = (unsigned short*)p; p += NXPP * 2;
    unsigned short* wout = (unsigned short*)p; p += NOUT * 2;
    unsigned short* wdt  = (unsigned short*)p; p += NDTW * 2;
    unsigned short* w1t  = (unsigned short*)p; p += NHW1 * 2;
    unsigned short* w2t  = (unsigned short*)p; p += NHW2 * 2;
    unsigned short* u  = (unsigned short*)p;   p += Mc * DMV * 2;
    unsigned short* t  = (unsigned short*)p;   p += Mc * DMV * 2;
    unsigned short* xz = (unsigned short*)p;   p += Mc * 2560 * 2;
    unsigned short* xc = (unsigned short*)p;   p += Mc * DIV * 2;
    unsigned short* dbc = (unsigned short*)p;  p += Mc * DBLD * 2;
    unsigned short* delta = (unsigned short*)p; p += Mc * DIV * 2;
    unsigned short* hfin = (unsigned short*)p; p += (long)Bc * NCHUNK * DIV * NST * 2;
    float* sumd = (float*)p;

    // one-time (per launch) weight conversion
    convert_kernel<<<(unsigned)((NLIN / 4 + 255) / 256), 256, 0, stream>>>(lin_w, wlin, NLIN / 4);
    convert_kernel<<<(unsigned)((NINP / 4 + 255) / 256), 256, 0, stream>>>(inproj_w, winp, NINP / 4);
    convert_kernel<<<(unsigned)((NOUT / 4 + 255) / 256), 256, 0, stream>>>(outproj_w, wout, NOUT / 4);
    convert_xp_kernel<<<(unsigned)((NXPP + 255) / 256), 256, 0, stream>>>(xproj_w, wxp);
    convert_dtw_kernel<<<(unsigned)((NDTW + 255) / 256), 256, 0, stream>>>(dtproj_w, wdt);
    convert_t2_kernel<<<(unsigned)((NHW1 + 255) / 256), 256, 0, stream>>>(s1_w1, w1t, 512, DMV);
    convert_t2_kernel<<<(unsigned)((NHW2 + 255) / 256), 256, 0, stream>>>(s1_w2, w2t, 512, 512);

    init_sm_kernel<<<1, 64, 0, stream>>>(sm);
    reduce_max_kernel<<<32, 256, 0, stream>>>(x, sm);

    for (int c = 0; c < nchunk_b; c++) {
        int b0 = c * Bc;
        fc_kernel<<<dim3(5, (unsigned)(Mc / 4)), 256, 0, stream>>>(
            x + (long)b0 * LSZ * 4, fc_w, fc_b, sm, u);

        for (int i = 0; i < NBLKV; i++) {
            const float* lb  = lin_b    + (long)i * DMV;
            const float* cw  = conv_w   + (long)i * DIV * DCV;
            const float* cb  = conv_b   + (long)i * DIV;
            const float* dpb = dtproj_b + (long)i * DIV;
            const float* al  = A_log    + (long)i * DIV * NST;
            const float* dd  = Dp       + (long)i * DIV;

            // lin + tanh: (Mc x320)@(320x320)^T -> t (bf16)
            gemm_mfma_kernel<1, 128, 64, 64, 256, unsigned short>
                <<<dim3(5, (unsigned)(Mc / 128)), 256, 0, stream>>>(
                u, wlin + (long)i * DMV * DMV, lb, t, DMV, DMV, DMV, DMV);
            // inproj: (Mc x320)@(2560x320)^T -> xz (bf16), 512-thread BM=256 tile
            gemm_mfma_kernel<0, 256, 128, 64, 512, unsigned short>
                <<<dim3(20, (unsigned)(Mc / 256)), 512, 0, stream>>>(
                t, winp + (long)i * 2 * DIV * DMV, nullptr, xz, 2 * DIV, DMV, DMV, 2 * DIV);
            // conv + silu (sliding window, 2 channels/thread)
            conv_kernel<<<dim3(5, LSZ / TCONV, Bc), 128, 0, stream>>>(xz, cw, cb, xc);
            // xproj: (Mc x1280)@(64x1280)^T (padded W) -> dbc (bf16, ld 56), BM=32
            gemm_mfma_kernel<0, 32, 64, 64, 256, unsigned short>
                <<<dim3(1, (unsigned)(Mc / 32)), 256, 0, stream>>>(
                xc, wxp + (long)i * 64 * DIV, nullptr, dbc,
                DTR + 2 * NST, DIV, DIV, DBLD);
            // delta = softplus(dbc[:, :20] @ dtw^T + b): K padded to 32, bf16 out
            gemm_mfma_kernel<4, 128, 128, 32, 256, unsigned short>
                <<<dim3(10, (unsigned)(Mc / 128)), 256, 0, stream>>>(
                dbc, wdt + (long)i * DIV * 32, dpb, delta, DIV, 32, DBLD, DIV);
            // chunked scan (CLEN=32, NCHUNK=64)
            scan_local_kernel<<<dim3(5, NCHUNK, Bc), 256, 0, stream>>>(
                xc, xz, dbc, delta, al, dd, hfin, sumd);
            scan_prefix_kernel<<<dim3(Bc * 80), 256, 0, stream>>>(hfin, sumd, al, Bc);
            scan_fix_kernel<<<dim3(5, NCHUNK, Bc), 256, 0, stream>>>(
                xz, dbc, delta, al, hfin);
            // outproj + elu: (Mc x1280)@(320x1280)^T -> u (bf16)
            gemm_mfma_kernel<3, 128, 64, 64, 256, unsigned short>
                <<<dim3(5, (unsigned)(Mc / 128)), 256, 0, stream>>>(
                xz, wout + (long)i * DMV * DIV, nullptr, u, DMV, DIV, 2 * DIV, DMV);
        }

        // fused head on last token of each batch in chunk
        head_kernel<<<Bc, 512, 0, stream>>>(u, w1t, s1_b1, w2t, s1_b2,
                                            s1_w3, s1_b3, sm, (float*)d_out + b0);
    }
}